// Round 7
// baseline (362.162 us; speedup 1.0000x reference)
//
#include <hip/hip_runtime.h>
#include <math.h>

typedef __attribute__((ext_vector_type(8))) short short8;
typedef __attribute__((ext_vector_type(4))) float f32x4;

// ---------------- helpers ----------------
__device__ __forceinline__ float wred_sum(float v) {
#pragma unroll
  for (int off = 32; off; off >>= 1) v += __shfl_xor(v, off, 64);
  return v;
}
__device__ __forceinline__ float wred_max(float v) {
#pragma unroll
  for (int off = 32; off; off >>= 1) v = fmaxf(v, __shfl_xor(v, off, 64));
  return v;
}
__device__ __forceinline__ unsigned f2key(float x) {
  unsigned b = __float_as_uint(x);
  return (b & 0x80000000u) ? ~b : (b | 0x80000000u);
}
__device__ __forceinline__ float key2f(unsigned k) {
  unsigned b = (k & 0x80000000u) ? (k & 0x7FFFFFFFu) : ~k;
  return __uint_as_float(b);
}
// bf16 <-> f32
__device__ __forceinline__ float b2f(unsigned short u) {
  return __uint_as_float(((unsigned)u) << 16);
}
__device__ __forceinline__ unsigned short f2b(float f) {
  unsigned b = __float_as_uint(f);
  return (unsigned short)((b + 0x7FFFu + ((b >> 16) & 1u)) >> 16);
}

// ---------------- f32 -> bf16 cast (6 segments, one launch) ----------------
__global__ __launch_bounds__(256) void k_cast6(
    const float* __restrict__ s0, ushort* __restrict__ d0, int n0,
    const float* __restrict__ s1, ushort* __restrict__ d1, int n1,
    const float* __restrict__ s2, ushort* __restrict__ d2, int n2,
    const float* __restrict__ s3, ushort* __restrict__ d3, int n3,
    const float* __restrict__ s4, ushort* __restrict__ d4, int n4,
    const float* __restrict__ s5, ushort* __restrict__ d5, int n5) {
  int t = (blockIdx.x * 256 + threadIdx.x) * 4;
  const float* s; ushort* d; int off = t;
  if (off < n0) { s = s0; d = d0; }
  else { off -= n0;
    if (off < n1) { s = s1; d = d1; }
    else { off -= n1;
      if (off < n2) { s = s2; d = d2; }
      else { off -= n2;
        if (off < n3) { s = s3; d = d3; }
        else { off -= n3;
          if (off < n4) { s = s4; d = d4; }
          else { off -= n4;
            if (off < n5) { s = s5; d = d5; }
            else return; } } } } }
  float4 v = *(const float4*)(s + off);
  ushort4 o;
  o.x = f2b(v.x); o.y = f2b(v.y); o.z = f2b(v.z); o.w = f2b(v.w);
  *(ushort4*)(d + off) = o;
}

// ---------------- self-loop mean edge_attr + degree count ----------------
__global__ __launch_bounds__(256) void k_count_ea(const int* __restrict__ dst,
    const float* __restrict__ ea, int* __restrict__ cnt_i,
    float* __restrict__ sum_ea, int E) {
  int e = blockIdx.x * 256 + threadIdx.x;
  if (e >= E) return;
  int d = dst[e];
  atomicAdd(&cnt_i[d], 1);
  atomicAdd(&sum_ea[d], ea[e]);
}

// exclusive scan of (cnt+1) over N nodes -> row_start[N+1], cursor copy
// also computes mean_ea = sum_ea / max(cnt,1)
__global__ __launch_bounds__(1024) void k_scan(const int* __restrict__ cnt_i,
    const float* __restrict__ sum_ea, float* __restrict__ mean_ea,
    int* __restrict__ row_st, int* __restrict__ cursor, int N) {
  __shared__ int sums[1024];
  int tid = threadIdx.x;
  int per = (N + 1023) / 1024;
  int begin = tid * per, end = min(begin + per, N);
  int s = 0;
  for (int i = begin; i < end; ++i) {
    int c = cnt_i[i];
    s += c + 1;
    mean_ea[i] = sum_ea[i] / fmaxf((float)c, 1.0f);
  }
  sums[tid] = s;
  __syncthreads();
  for (int off = 1; off < 1024; off <<= 1) {
    int v = (tid >= off) ? sums[tid - off] : 0;
    __syncthreads();
    sums[tid] += v;
    __syncthreads();
  }
  int prefix = (tid == 0) ? 0 : sums[tid - 1];
  for (int i = begin; i < end; ++i) {
    row_st[i] = prefix;
    cursor[i] = prefix;
    prefix += cnt_i[i] + 1;
  }
  if (tid == 0) row_st[N] = sums[1023];
}

// scatter: store source-node id and edge value directly (no perm indirection)
__global__ __launch_bounds__(256) void k_scatter(const int* __restrict__ dst,
    const int* __restrict__ src, const float* __restrict__ ea,
    const float* __restrict__ mean_ea, int* __restrict__ cursor,
    int* __restrict__ srcp, float* __restrict__ eap, int E, int E2) {
  int e = blockIdx.x * 256 + threadIdx.x;
  if (e >= E2) return;
  int d, sn; float av;
  if (e < E) { d = dst[e]; sn = src[e]; av = ea[e]; }
  else { d = e - E; sn = d; av = mean_ea[d]; }
  int pos = atomicAdd(&cursor[d], 1);
  srcp[pos] = sn;
  eap[pos] = av;
}

// ---------------- bf16 MFMA GEMM: C[M,Nc](bf16) = A[M,K](bf16) * W[Nc,K](bf16)^T + bias(f32)
__global__ __launch_bounds__(256) void k_gemm_mfma2(const ushort* __restrict__ A,
    const ushort* __restrict__ W0, const float* __restrict__ b0, ushort* __restrict__ C0,
    const ushort* __restrict__ W1, const float* __restrict__ b1, ushort* __restrict__ C1,
    int M, int Nc, int K) {
  const ushort* W = blockIdx.z ? W1 : W0;
  const float* bias = blockIdx.z ? b1 : b0;
  ushort* C = blockIdx.z ? C1 : C0;
  int wave = threadIdx.x >> 6, lane = threadIdx.x & 63;
  int m0 = blockIdx.x * 64 + wave * 16;
  int n0 = blockIdx.y * 64;
  int r = lane & 15, g = lane >> 4;
  f32x4 acc[4] = {};
  int am = min(m0 + r, M - 1);
  const ushort* Arow = A + (size_t)am * K + g * 8;
  const ushort* Wrow = W + (size_t)(n0 + r) * K + g * 8;
  for (int k0 = 0; k0 < K; k0 += 32) {
    short8 a = *(const short8*)(const void*)(Arow + k0);
#pragma unroll
    for (int c = 0; c < 4; ++c) {
      short8 b = *(const short8*)(const void*)(Wrow + (size_t)c * 16 * K + k0);
      acc[c] = __builtin_amdgcn_mfma_f32_16x16x32_bf16(a, b, acc[c], 0, 0, 0);
    }
  }
#pragma unroll
  for (int c = 0; c < 4; ++c) {
    int gn = n0 + c * 16 + r;
    float bv = bias[gn];
#pragma unroll
    for (int j = 0; j < 4; ++j) {
      int gm = m0 + g * 4 + j;
      if (gm < M) C[(size_t)gm * Nc + gn] = f2b(acc[c][j] + bv);
    }
  }
}

// ---------------- layer 1 fused: scores + online softmax + aggregation ----------------
__global__ __launch_bounds__(256) void k_fused1(const ushort* __restrict__ xl,
    const ushort* __restrict__ xr, const int* __restrict__ srcp,
    const float* __restrict__ eap, const int* __restrict__ row_st,
    const float* __restrict__ We, const float* __restrict__ att,
    const float* __restrict__ bias, ushort* __restrict__ out, int N) {
  int n = blockIdx.x * 4 + (threadIdx.x >> 6);
  int lane = threadIdx.x & 63;
  if (n >= N) return;
  const float4 We4 = ((const float4*)We)[lane];
  const float4 at4 = ((const float4*)att)[lane];
  ushort4 xru = *(const ushort4*)(xr + (size_t)n * 256 + lane * 4);
  float xrx = b2f(xru.x), xry = b2f(xru.y), xrz = b2f(xru.z), xrw = b2f(xru.w);
  int a = row_st[n], b = row_st[n + 1];
  float m = -INFINITY, den = 0.f;
  float ax = 0.f, ay = 0.f, az = 0.f, aw = 0.f;
  int sn_nx = srcp[a];
  float av_nx = eap[a];
  for (int i = a; i < b; ++i) {
    int sn = sn_nx;
    float av = av_nx;
    ushort4 xu = *(const ushort4*)(xl + (size_t)sn * 256 + lane * 4);
    if (i + 1 < b) { sn_nx = srcp[i + 1]; av_nx = eap[i + 1]; }
    float x0 = b2f(xu.x), x1 = b2f(xu.y), x2 = b2f(xu.z), x3 = b2f(xu.w);
    float vx = x0 + xrx + av * We4.x; vx = vx > 0.f ? vx : 0.2f * vx;
    float vy = x1 + xry + av * We4.y; vy = vy > 0.f ? vy : 0.2f * vy;
    float vz = x2 + xrz + av * We4.z; vz = vz > 0.f ? vz : 0.2f * vz;
    float vw = x3 + xrw + av * We4.w; vw = vw > 0.f ? vw : 0.2f * vw;
    float t = at4.x * vx + at4.y * vy + at4.z * vz + at4.w * vw;
    t += __shfl_xor(t, 1, 16);
    t += __shfl_xor(t, 2, 16);
    t += __shfl_xor(t, 4, 16);
    t += __shfl_xor(t, 8, 16);
    if (t > m) {
      float sc = __expf(m - t);
      m = t;
      den *= sc; ax *= sc; ay *= sc; az *= sc; aw *= sc;
    }
    float ex = __expf(t - m);
    den += ex;
    ax += ex * x0; ay += ex * x1; az += ex * x2; aw += ex * x3;
  }
  float inv = 1.f / (den + 1e-16f);
  const float4 b4 = ((const float4*)bias)[lane];
  ushort4 o;
  o.x = f2b(fmaxf(ax * inv + b4.x, 0.f));
  o.y = f2b(fmaxf(ay * inv + b4.y, 0.f));
  o.z = f2b(fmaxf(az * inv + b4.z, 0.f));
  o.w = f2b(fmaxf(aw * inv + b4.w, 0.f));
  *(ushort4*)(out + (size_t)n * 256 + lane * 4) = o;
}

// ---------------- layer 2 fused (H=1, C=64) ----------------
__global__ __launch_bounds__(256) void k_fused2(const ushort* __restrict__ xl,
    const ushort* __restrict__ xr, const int* __restrict__ srcp,
    const float* __restrict__ eap, const int* __restrict__ row_st,
    const float* __restrict__ We, const float* __restrict__ att,
    const float* __restrict__ bias, float* __restrict__ out, int N) {
  int n = blockIdx.x * 4 + (threadIdx.x >> 6);
  int lane = threadIdx.x & 63;
  if (n >= N) return;
  const float Wev = We[lane];
  const float atv = att[lane];
  const float xrv = b2f(xr[(size_t)n * 64 + lane]);
  int a = row_st[n], b = row_st[n + 1];
  float m = -INFINITY, den = 0.f, acc = 0.f;
  int sn_nx = srcp[a];
  float av_nx = eap[a];
  for (int i = a; i < b; ++i) {
    int sn = sn_nx;
    float av = av_nx;
    float xv = b2f(xl[(size_t)sn * 64 + lane]);
    if (i + 1 < b) { sn_nx = srcp[i + 1]; av_nx = eap[i + 1]; }
    float v = xv + xrv + av * Wev;
    v = v > 0.f ? v : 0.2f * v;
    float t = wred_sum(atv * v);
    if (t > m) {
      float sc = __expf(m - t);
      m = t; den *= sc; acc *= sc;
    }
    float ex = __expf(t - m);
    den += ex;
    acc += ex * xv;
  }
  float v = acc / (den + 1e-16f) + bias[lane];
  out[(size_t)n * 64 + lane] = v > 0.f ? v : 0.f;
}

// ---------------- global mean pool (+ aflag scatter in block 0) ----------------
__global__ __launch_bounds__(256) void k_pool(const float* __restrict__ h2,
    float* __restrict__ g_sum, const int* __restrict__ actions,
    unsigned char* __restrict__ aflag, int n_act, int N) {
  __shared__ float red[4][64];
  int b = blockIdx.x, tid = threadIdx.x;
  if (b == 0 && tid < n_act) aflag[actions[tid]] = 1;
  int lane = tid & 63, w = tid >> 6;
  int rows_per = (N + gridDim.x - 1) / gridDim.x;
  int r0 = b * rows_per, r1 = min(r0 + rows_per, N);
  float s = 0;
  for (int r = r0 + w; r < r1; r += 4) s += h2[(size_t)r * 64 + lane];
  red[w][lane] = s;
  __syncthreads();
  if (w == 0) {
    float v = red[0][lane] + red[1][lane] + red[2][lane] + red[3][lane];
    atomicAdd(&g_sum[lane], v);
  }
}

// mean -> g, state potential, sigmoid(alpha)
__global__ void k_head(const float* __restrict__ g_sum, const float* __restrict__ Wp,
    const float* __restrict__ bp, const float* __restrict__ alpha,
    float* __restrict__ g, float* __restrict__ out, int N, int NA) {
  int lane = threadIdx.x;
  float gv = g_sum[lane] / (float)N;
  g[lane] = gv;
  float t = wred_sum(gv * Wp[lane]);
  if (lane == 0) {
    float sp = t + bp[0];
    out[NA] = sp > 0.f ? sp : 0.f;
    out[NA + 1] = 1.f / (1.f + __expf(-alpha[0]));
  }
}

// ---------------- masked logits: bf16 Wf, coalesced GEMV, 1 atomic/block ----------------
__global__ __launch_bounds__(256) void k_logits(const float* __restrict__ g,
    const ushort* __restrict__ Wfb, const float* __restrict__ bf,
    const unsigned char* __restrict__ aflag, const int* __restrict__ src,
    const int* __restrict__ dst, float* __restrict__ logits,
    unsigned* __restrict__ gmax_key, int E, int NA) {
  __shared__ float gs[64];
  __shared__ float wmax[4];
  int tid = threadIdx.x;
  if (tid < 64) gs[tid] = g[tid];
  __syncthreads();
  int l16 = tid & 15;
  float4 gv = ((const float4*)gs)[l16];
  float gmaxl = -INFINITY;
  for (int row = blockIdx.x * 16 + (tid >> 4); row < NA; row += gridDim.x * 16) {
    float val = -INFINITY;
    bool keep = (!aflag[row]) && (row >= E || src[row] != dst[row]);
    if (keep) {
      ushort4 w = *(const ushort4*)(Wfb + (size_t)row * 64 + l16 * 4);
      float acc = b2f(w.x) * gv.x + b2f(w.y) * gv.y + b2f(w.z) * gv.z + b2f(w.w) * gv.w;
      acc += __shfl_xor(acc, 1, 16);
      acc += __shfl_xor(acc, 2, 16);
      acc += __shfl_xor(acc, 4, 16);
      acc += __shfl_xor(acc, 8, 16);
      val = acc + bf[row];
    }
    if (l16 == 0) logits[row] = val;
    gmaxl = fmaxf(gmaxl, val);
  }
  gmaxl = wred_max(gmaxl);
  if ((tid & 63) == 0) wmax[tid >> 6] = gmaxl;
  __syncthreads();
  if (tid == 0) {
    float m = fmaxf(fmaxf(wmax[0], wmax[1]), fmaxf(wmax[2], wmax[3]));
    atomicMax(gmax_key, f2key(m));
  }
}

// ---------------- exp pass: float4, 1 atomic/block ----------------
__global__ __launch_bounds__(256) void k_exp(float* __restrict__ logits,
    const unsigned* __restrict__ gmax_key, float* __restrict__ gsum, int NA) {
  __shared__ float wsum[4];
  int i = (blockIdx.x * 256 + threadIdx.x) * 4;
  float gmax = key2f(*gmax_key);
  float s = 0.f;
  if (i < NA) {
    float4 v = *(const float4*)(logits + i);   // logits buffer padded past NA
    float4 e;
    e.x = (i + 0 < NA && v.x != -INFINITY) ? __expf(v.x - gmax) : 0.f;
    e.y = (i + 1 < NA && v.y != -INFINITY) ? __expf(v.y - gmax) : 0.f;
    e.z = (i + 2 < NA && v.z != -INFINITY) ? __expf(v.z - gmax) : 0.f;
    e.w = (i + 3 < NA && v.w != -INFINITY) ? __expf(v.w - gmax) : 0.f;
    *(float4*)(logits + i) = e;
    s = e.x + e.y + e.z + e.w;
  }
  s = wred_sum(s);
  if ((threadIdx.x & 63) == 0) wsum[threadIdx.x >> 6] = s;
  __syncthreads();
  if (threadIdx.x == 0)
    atomicAdd(gsum, wsum[0] + wsum[1] + wsum[2] + wsum[3]);
}

__global__ __launch_bounds__(256) void k_norm(const float* __restrict__ logits,
    const float* __restrict__ gsum, float* __restrict__ out, int NA) {
  int i = (blockIdx.x * 256 + threadIdx.x) * 4;
  if (i >= NA) return;
  float inv = 1.f / (*gsum);
  if (i + 3 < NA) {
    float4 v = *(const float4*)(logits + i);
    float4 o;
    o.x = v.x * inv; o.y = v.y * inv; o.z = v.z * inv; o.w = v.w * inv;
    *(float4*)(out + i) = o;
  } else {
    for (int j = i; j < NA; ++j) out[j] = logits[j] * inv;
  }
}

// ---------------- launch ----------------
extern "C" void kernel_launch(void* const* d_in, const int* in_sizes, int n_in,
                              void* d_out, int out_size, void* d_ws, size_t ws_size,
                              hipStream_t stream) {
  const float* x      = (const float*)d_in[0];
  const int*   eidx   = (const int*)d_in[1];
  const float* eattr  = (const float*)d_in[2];
  const int*   actions= (const int*)d_in[3];
  const float* Wl1 = (const float*)d_in[4];
  const float* bl1 = (const float*)d_in[5];
  const float* Wr1 = (const float*)d_in[6];
  const float* br1 = (const float*)d_in[7];
  const float* We1 = (const float*)d_in[8];
  const float* att1= (const float*)d_in[9];
  const float* bias1=(const float*)d_in[10];
  const float* Wl2 = (const float*)d_in[11];
  const float* bl2 = (const float*)d_in[12];
  const float* Wr2 = (const float*)d_in[13];
  const float* br2 = (const float*)d_in[14];
  const float* We2 = (const float*)d_in[15];
  const float* att2= (const float*)d_in[16];
  const float* bias2=(const float*)d_in[17];
  const float* Wf  = (const float*)d_in[18];
  const float* bf  = (const float*)d_in[19];
  const float* Wp  = (const float*)d_in[20];
  const float* bp  = (const float*)d_in[21];
  const float* alpha=(const float*)d_in[22];

  const int F = 128;
  const int N = in_sizes[0] / F;       // 20000
  const int E = in_sizes[2];           // 400000
  const int E2 = E + N;
  const int NA = E + 1;
  const int n_act = in_sizes[3];
  const int* src = eidx;
  const int* dst = eidx + E;
  const int hid = 64;

  float* ws = (float*)d_ws;
  size_t p = 0;
  int*      cnt_i    = (int*)(ws + p);      p += (size_t)N;
  float*    sum_ea   = ws + p;              p += (size_t)N;
  float*    g_sum    = ws + p;              p += 64;
  unsigned* gmax_key = (unsigned*)(ws + p); p += 64;
  float*    gsum     = ws + p;              p += 64;
  unsigned char* aflag = (unsigned char*)(ws + p); p += ((size_t)NA + 3) / 4;
  size_t zero_bytes = p * sizeof(float);    // one memset covers all of the above
  float*    g        = ws + p;              p += 64;
  float*    mean_ea  = ws + p;              p += (size_t)N;
  int*      row_st   = (int*)(ws + p);      p += (size_t)N + 64;
  int*      cursor   = (int*)(ws + p);      p += (size_t)N;
  int*      srcp     = (int*)(ws + p);      p += (size_t)E2;
  float*    eap      = ws + p;              p += (size_t)E2;
  float*    logits   = ws + p;              p += (size_t)NA + 64;
  p = (p + 3) & ~(size_t)3;                 // 16B align for bf16 region
  float*    h2       = ws + p;              p += (size_t)N * hid;
  ushort* ub = (ushort*)(ws + p);
  size_t q = 0;
  ushort* xb   = ub + q; q += (size_t)N * F;        // x bf16
  ushort* wl1b = ub + q; q += (size_t)256 * 128;
  ushort* wr1b = ub + q; q += (size_t)256 * 128;
  ushort* wl2b = ub + q; q += (size_t)64 * 256;
  ushort* wr2b = ub + q; q += (size_t)64 * 256;
  ushort* wfb  = ub + q; q += (size_t)NA * 64;      // Wf rows [0,NA) bf16
  ushort* xl1b = ub + q; q += (size_t)N * 256;
  ushort* xr1b = ub + q; q += (size_t)N * 256;
  ushort* h1b  = ub + q; q += (size_t)N * 256;
  ushort* xl2b = ub + q; q += (size_t)N * 64;
  ushort* xr2b = ub + q; q += (size_t)N * 64;

  float* out = (float*)d_out;

  hipMemsetAsync(d_ws, 0, zero_bytes, stream);

  // casts: x + 4 weight matrices + Wf -> bf16
  {
    int n0 = N * F, n1 = 256 * 128, n2 = 256 * 128, n3 = 64 * 256, n4 = 64 * 256;
    int n5 = NA * 64;   // 25.6M, divisible by 4
    long long tot = (long long)n0 + n1 + n2 + n3 + n4 + n5;
    int tot4 = (int)(tot / 4);
    k_cast6<<<(tot4 + 255) / 256, 256, 0, stream>>>(
        x, xb, n0, Wl1, wl1b, n1, Wr1, wr1b, n2, Wl2, wl2b, n3, Wr2, wr2b, n4,
        Wf, wfb, n5);
  }

  // CSR build + self-loop edge attr
  k_count_ea<<<(E + 255) / 256, 256, 0, stream>>>(dst, eattr, cnt_i, sum_ea, E);
  k_scan<<<1, 1024, 0, stream>>>(cnt_i, sum_ea, mean_ea, row_st, cursor, N);
  k_scatter<<<(E2 + 255) / 256, 256, 0, stream>>>(dst, src, eattr, mean_ea,
                                                  cursor, srcp, eap, E, E2);

  // layer 1 projections (bf16 MFMA): xl1b, xr1b in one launch
  {
    dim3 g1((N + 63) / 64, 256 / 64, 2);
    k_gemm_mfma2<<<g1, 256, 0, stream>>>(xb, wl1b, bl1, xl1b, wr1b, br1, xr1b,
                                         N, 256, 128);
  }
  k_fused1<<<(N + 3) / 4, 256, 0, stream>>>(xl1b, xr1b, srcp, eap, row_st,
                                            We1, att1, bias1, h1b, N);

  // layer 2 projections from h1b: xl2b, xr2b in one launch
  {
    dim3 g2((N + 63) / 64, 1, 2);
    k_gemm_mfma2<<<g2, 256, 0, stream>>>(h1b, wl2b, bl2, xl2b, wr2b, br2, xr2b,
                                         N, 64, 256);
  }
  k_fused2<<<(N + 3) / 4, 256, 0, stream>>>(xl2b, xr2b, srcp, eap, row_st,
                                            We2, att2, bias2, h2, N);

  // head
  k_pool<<<128, 256, 0, stream>>>(h2, g_sum, actions, aflag, n_act, N);
  k_head<<<1, 64, 0, stream>>>(g_sum, Wp, bp, alpha, g, out, N, NA);
  k_logits<<<2048, 256, 0, stream>>>(g, wfb, bf, aflag, src, dst,
                                     logits, gmax_key, E, NA);
  int nb4 = (NA + 1023) / 1024;
  k_exp<<<nb4, 256, 0, stream>>>(logits, gmax_key, gsum, NA);
  k_norm<<<nb4, 256, 0, stream>>>(logits, gsum, out, NA);
}

// Round 8
// 320.680 us; speedup vs baseline: 1.1294x; 1.1294x over previous
//
#include <hip/hip_runtime.h>
#include <math.h>

typedef __attribute__((ext_vector_type(8))) short short8;
typedef __attribute__((ext_vector_type(4))) float f32x4;

// ---------------- helpers ----------------
__device__ __forceinline__ float wred_sum(float v) {
#pragma unroll
  for (int off = 32; off; off >>= 1) v += __shfl_xor(v, off, 64);
  return v;
}
__device__ __forceinline__ float wred_max(float v) {
#pragma unroll
  for (int off = 32; off; off >>= 1) v = fmaxf(v, __shfl_xor(v, off, 64));
  return v;
}
__device__ __forceinline__ unsigned f2key(float x) {
  unsigned b = __float_as_uint(x);
  return (b & 0x80000000u) ? ~b : (b | 0x80000000u);
}
__device__ __forceinline__ float key2f(unsigned k) {
  unsigned b = (k & 0x80000000u) ? (k & 0x7FFFFFFFu) : ~k;
  return __uint_as_float(b);
}
// bf16 <-> f32
__device__ __forceinline__ float b2f(unsigned short u) {
  return __uint_as_float(((unsigned)u) << 16);
}
__device__ __forceinline__ unsigned short f2b(float f) {
  unsigned b = __float_as_uint(f);
  return (unsigned short)((b + 0x7FFFu + ((b >> 16) & 1u)) >> 16);
}

// ---------------- f32 -> bf16 cast (5 segments, one launch) ----------------
__global__ __launch_bounds__(256) void k_cast5(
    const float* __restrict__ s0, ushort* __restrict__ d0, int n0,
    const float* __restrict__ s1, ushort* __restrict__ d1, int n1,
    const float* __restrict__ s2, ushort* __restrict__ d2, int n2,
    const float* __restrict__ s3, ushort* __restrict__ d3, int n3,
    const float* __restrict__ s4, ushort* __restrict__ d4, int n4) {
  int t = (blockIdx.x * 256 + threadIdx.x) * 4;
  const float* s; ushort* d; int off = t;
  if (off < n0) { s = s0; d = d0; }
  else { off -= n0;
    if (off < n1) { s = s1; d = d1; }
    else { off -= n1;
      if (off < n2) { s = s2; d = d2; }
      else { off -= n2;
        if (off < n3) { s = s3; d = d3; }
        else { off -= n3;
          if (off < n4) { s = s4; d = d4; }
          else return; } } } }
  float4 v = *(const float4*)(s + off);
  ushort4 o;
  o.x = f2b(v.x); o.y = f2b(v.y); o.z = f2b(v.z); o.w = f2b(v.w);
  *(ushort4*)(d + off) = o;
}

// ---------------- Wf transpose-cast: wfT8[k8][row][j] = bf16(Wf[row][k8*8+j]) ----
// 64-row tiles; reads coalesced f32, writes coalesced bf16 (16B chunks per (k8,row)).
__global__ __launch_bounds__(256) void k_twf(const float* __restrict__ Wf,
    ushort* __restrict__ wfT8, int NAp) {
  __shared__ ushort lds[64][68];  // pad 4 ushorts: 136B row stride
  int row0 = blockIdx.x * 64;
  int t = threadIdx.x;
  int r = t >> 2, cg = t & 3;
  const float* srcp = Wf + ((size_t)(row0 + r)) * 64 + cg * 16;
#pragma unroll
  for (int u = 0; u < 4; ++u) {
    float4 v = *(const float4*)(srcp + u * 4);
    int c = cg * 16 + u * 4;
    lds[r][c + 0] = f2b(v.x); lds[r][c + 1] = f2b(v.y);
    lds[r][c + 2] = f2b(v.z); lds[r][c + 3] = f2b(v.w);
  }
  __syncthreads();
  int k8 = t >> 5, rg = t & 31;
#pragma unroll
  for (int h = 0; h < 2; ++h) {
    int r2 = rg + h * 32;
    ushort4 wa = *(const ushort4*)(&lds[r2][k8 * 8]);
    ushort4 wb = *(const ushort4*)(&lds[r2][k8 * 8 + 4]);
    ushort* dst = wfT8 + ((size_t)k8 * NAp + row0 + r2) * 8;
    *(ushort4*)(dst) = wa;
    *(ushort4*)(dst + 4) = wb;
  }
}

// ---------------- self-loop mean edge_attr + degree count ----------------
__global__ __launch_bounds__(256) void k_count_ea(const int* __restrict__ dst,
    const float* __restrict__ ea, int* __restrict__ cnt_i,
    float* __restrict__ sum_ea, int E) {
  int e = blockIdx.x * 256 + threadIdx.x;
  if (e >= E) return;
  int d = dst[e];
  atomicAdd(&cnt_i[d], 1);
  atomicAdd(&sum_ea[d], ea[e]);
}

// exclusive scan of (cnt+1) -> row_start[N+1], cursor; mean_ea folded in
__global__ __launch_bounds__(1024) void k_scan(const int* __restrict__ cnt_i,
    const float* __restrict__ sum_ea, float* __restrict__ mean_ea,
    int* __restrict__ row_st, int* __restrict__ cursor, int N) {
  __shared__ int sums[1024];
  int tid = threadIdx.x;
  int per = (N + 1023) / 1024;
  int begin = tid * per, end = min(begin + per, N);
  int s = 0;
  for (int i = begin; i < end; ++i) {
    int c = cnt_i[i];
    s += c + 1;
    mean_ea[i] = sum_ea[i] / fmaxf((float)c, 1.0f);
  }
  sums[tid] = s;
  __syncthreads();
  for (int off = 1; off < 1024; off <<= 1) {
    int v = (tid >= off) ? sums[tid - off] : 0;
    __syncthreads();
    sums[tid] += v;
    __syncthreads();
  }
  int prefix = (tid == 0) ? 0 : sums[tid - 1];
  for (int i = begin; i < end; ++i) {
    row_st[i] = prefix;
    cursor[i] = prefix;
    prefix += cnt_i[i] + 1;
  }
  if (tid == 0) row_st[N] = sums[1023];
}

// scatter: store source-node id and edge value directly
__global__ __launch_bounds__(256) void k_scatter(const int* __restrict__ dst,
    const int* __restrict__ src, const float* __restrict__ ea,
    const float* __restrict__ mean_ea, int* __restrict__ cursor,
    int* __restrict__ srcp, float* __restrict__ eap, int E, int E2) {
  int e = blockIdx.x * 256 + threadIdx.x;
  if (e >= E2) return;
  int d, sn; float av;
  if (e < E) { d = dst[e]; sn = src[e]; av = ea[e]; }
  else { d = e - E; sn = d; av = mean_ea[d]; }
  int pos = atomicAdd(&cursor[d], 1);
  srcp[pos] = sn;
  eap[pos] = av;
}

// ---------------- bf16 MFMA GEMM ----------------
__global__ __launch_bounds__(256) void k_gemm_mfma2(const ushort* __restrict__ A,
    const ushort* __restrict__ W0, const float* __restrict__ b0, ushort* __restrict__ C0,
    const ushort* __restrict__ W1, const float* __restrict__ b1, ushort* __restrict__ C1,
    int M, int Nc, int K) {
  const ushort* W = blockIdx.z ? W1 : W0;
  const float* bias = blockIdx.z ? b1 : b0;
  ushort* C = blockIdx.z ? C1 : C0;
  int wave = threadIdx.x >> 6, lane = threadIdx.x & 63;
  int m0 = blockIdx.x * 64 + wave * 16;
  int n0 = blockIdx.y * 64;
  int r = lane & 15, g = lane >> 4;
  f32x4 acc[4] = {};
  int am = min(m0 + r, M - 1);
  const ushort* Arow = A + (size_t)am * K + g * 8;
  const ushort* Wrow = W + (size_t)(n0 + r) * K + g * 8;
  for (int k0 = 0; k0 < K; k0 += 32) {
    short8 a = *(const short8*)(const void*)(Arow + k0);
#pragma unroll
    for (int c = 0; c < 4; ++c) {
      short8 b = *(const short8*)(const void*)(Wrow + (size_t)c * 16 * K + k0);
      acc[c] = __builtin_amdgcn_mfma_f32_16x16x32_bf16(a, b, acc[c], 0, 0, 0);
    }
  }
#pragma unroll
  for (int c = 0; c < 4; ++c) {
    int gn = n0 + c * 16 + r;
    float bv = bias[gn];
#pragma unroll
    for (int j = 0; j < 4; ++j) {
      int gm = m0 + g * 4 + j;
      if (gm < M) C[(size_t)gm * Nc + gn] = f2b(acc[c][j] + bv);
    }
  }
}

// ---------------- layer 1 fused: 32 lanes/node, 2 nodes/wave, ushort8 loads ------
__global__ __launch_bounds__(256) void k_fused1(const ushort* __restrict__ xl,
    const ushort* __restrict__ xr, const int* __restrict__ srcp,
    const float* __restrict__ eap, const int* __restrict__ row_st,
    const float* __restrict__ We, const float* __restrict__ att,
    const float* __restrict__ bias, ushort* __restrict__ out, int N) {
  int tid = threadIdx.x;
  int lane = tid & 63;
  int half = lane >> 5, l32 = lane & 31;
  int n = blockIdx.x * 8 + (tid >> 6) * 2 + half;
  if (n >= N) return;
  int c0 = l32 * 8;
  float4 Wa = *(const float4*)(We + c0), Wb = *(const float4*)(We + c0 + 4);
  float4 Aa = *(const float4*)(att + c0), Ab = *(const float4*)(att + c0 + 4);
  float Wev[8] = {Wa.x, Wa.y, Wa.z, Wa.w, Wb.x, Wb.y, Wb.z, Wb.w};
  float atv[8] = {Aa.x, Aa.y, Aa.z, Aa.w, Ab.x, Ab.y, Ab.z, Ab.w};
  short8 xru = *(const short8*)(const void*)(xr + (size_t)n * 256 + c0);
  float xrf[8];
#pragma unroll
  for (int j = 0; j < 8; ++j) xrf[j] = b2f((unsigned short)xru[j]);
  int a = row_st[n], b = row_st[n + 1];
  float m = -INFINITY, den = 0.f;
  float acc[8] = {};
  int sn_nx = srcp[a];
  float av_nx = eap[a];
  for (int i = a; i < b; ++i) {
    int sn = sn_nx;
    float av = av_nx;
    short8 xu = *(const short8*)(const void*)(xl + (size_t)sn * 256 + c0);
    if (i + 1 < b) { sn_nx = srcp[i + 1]; av_nx = eap[i + 1]; }
    float x[8];
    float t = 0.f;
#pragma unroll
    for (int j = 0; j < 8; ++j) {
      x[j] = b2f((unsigned short)xu[j]);
      float v = x[j] + xrf[j] + av * Wev[j];
      v = v > 0.f ? v : 0.2f * v;
      t += atv[j] * v;
    }
    t += __shfl_xor(t, 1, 8);
    t += __shfl_xor(t, 2, 8);
    t += __shfl_xor(t, 4, 8);
    if (t > m) {
      float sc = __expf(m - t);
      m = t; den *= sc;
#pragma unroll
      for (int j = 0; j < 8; ++j) acc[j] *= sc;
    }
    float ex = __expf(t - m);
    den += ex;
#pragma unroll
    for (int j = 0; j < 8; ++j) acc[j] += ex * x[j];
  }
  float inv = 1.f / (den + 1e-16f);
  float4 Ba = *(const float4*)(bias + c0), Bb = *(const float4*)(bias + c0 + 4);
  float bv[8] = {Ba.x, Ba.y, Ba.z, Ba.w, Bb.x, Bb.y, Bb.z, Bb.w};
  short8 o;
#pragma unroll
  for (int j = 0; j < 8; ++j) o[j] = (short)f2b(fmaxf(acc[j] * inv + bv[j], 0.f));
  *(short8*)(void*)(out + (size_t)n * 256 + c0) = o;
}

// ---------------- layer 2 fused: 8 lanes/node, 8 nodes/wave ----------------
__global__ __launch_bounds__(256) void k_fused2(const ushort* __restrict__ xl,
    const ushort* __restrict__ xr, const int* __restrict__ srcp,
    const float* __restrict__ eap, const int* __restrict__ row_st,
    const float* __restrict__ We, const float* __restrict__ att,
    const float* __restrict__ bias, float* __restrict__ out, int N) {
  int tid = threadIdx.x;
  int lane = tid & 63;
  int sub = lane >> 3, l8 = lane & 7;
  int n = blockIdx.x * 32 + (tid >> 6) * 8 + sub;
  if (n >= N) return;
  int c0 = l8 * 8;
  float4 Wa = *(const float4*)(We + c0), Wb = *(const float4*)(We + c0 + 4);
  float4 Aa = *(const float4*)(att + c0), Ab = *(const float4*)(att + c0 + 4);
  float Wev[8] = {Wa.x, Wa.y, Wa.z, Wa.w, Wb.x, Wb.y, Wb.z, Wb.w};
  float atv[8] = {Aa.x, Aa.y, Aa.z, Aa.w, Ab.x, Ab.y, Ab.z, Ab.w};
  short8 xru = *(const short8*)(const void*)(xr + (size_t)n * 64 + c0);
  float xrf[8];
#pragma unroll
  for (int j = 0; j < 8; ++j) xrf[j] = b2f((unsigned short)xru[j]);
  int a = row_st[n], b = row_st[n + 1];
  float m = -INFINITY, den = 0.f;
  float acc[8] = {};
  int sn_nx = srcp[a];
  float av_nx = eap[a];
  for (int i = a; i < b; ++i) {
    int sn = sn_nx;
    float av = av_nx;
    short8 xu = *(const short8*)(const void*)(xl + (size_t)sn * 64 + c0);
    if (i + 1 < b) { sn_nx = srcp[i + 1]; av_nx = eap[i + 1]; }
    float x[8];
    float t = 0.f;
#pragma unroll
    for (int j = 0; j < 8; ++j) {
      x[j] = b2f((unsigned short)xu[j]);
      float v = x[j] + xrf[j] + av * Wev[j];
      v = v > 0.f ? v : 0.2f * v;
      t += atv[j] * v;
    }
    t += __shfl_xor(t, 1, 8);
    t += __shfl_xor(t, 2, 8);
    t += __shfl_xor(t, 4, 8);
    if (t > m) {
      float sc = __expf(m - t);
      m = t; den *= sc;
#pragma unroll
      for (int j = 0; j < 8; ++j) acc[j] *= sc;
    }
    float ex = __expf(t - m);
    den += ex;
#pragma unroll
    for (int j = 0; j < 8; ++j) acc[j] += ex * x[j];
  }
  float inv = 1.f / (den + 1e-16f);
  float4 Ba = *(const float4*)(bias + c0), Bb = *(const float4*)(bias + c0 + 4);
  float4 o0, o1;
  o0.x = fmaxf(acc[0] * inv + Ba.x, 0.f);
  o0.y = fmaxf(acc[1] * inv + Ba.y, 0.f);
  o0.z = fmaxf(acc[2] * inv + Ba.z, 0.f);
  o0.w = fmaxf(acc[3] * inv + Ba.w, 0.f);
  o1.x = fmaxf(acc[4] * inv + Bb.x, 0.f);
  o1.y = fmaxf(acc[5] * inv + Bb.y, 0.f);
  o1.z = fmaxf(acc[6] * inv + Bb.z, 0.f);
  o1.w = fmaxf(acc[7] * inv + Bb.w, 0.f);
  *(float4*)(out + (size_t)n * 64 + c0) = o0;
  *(float4*)(out + (size_t)n * 64 + c0 + 4) = o1;
}

// ---------------- global mean pool (+ aflag scatter in block 0) ----------------
__global__ __launch_bounds__(256) void k_pool(const float* __restrict__ h2,
    float* __restrict__ g_sum, const int* __restrict__ actions,
    unsigned char* __restrict__ aflag, int n_act, int N) {
  __shared__ float red[4][64];
  int b = blockIdx.x, tid = threadIdx.x;
  if (b == 0 && tid < n_act) aflag[actions[tid]] = 1;
  int lane = tid & 63, w = tid >> 6;
  int rows_per = (N + gridDim.x - 1) / gridDim.x;
  int r0 = b * rows_per, r1 = min(r0 + rows_per, N);
  float s = 0;
  for (int r = r0 + w; r < r1; r += 4) s += h2[(size_t)r * 64 + lane];
  red[w][lane] = s;
  __syncthreads();
  if (w == 0) {
    float v = red[0][lane] + red[1][lane] + red[2][lane] + red[3][lane];
    atomicAdd(&g_sum[lane], v);
  }
}

// mean -> g, state potential, sigmoid(alpha)
__global__ void k_head(const float* __restrict__ g_sum, const float* __restrict__ Wp,
    const float* __restrict__ bp, const float* __restrict__ alpha,
    float* __restrict__ g, float* __restrict__ out, int N, int NA) {
  int lane = threadIdx.x;
  float gv = g_sum[lane] / (float)N;
  g[lane] = gv;
  float t = wred_sum(gv * Wp[lane]);
  if (lane == 0) {
    float sp = t + bp[0];
    out[NA] = sp > 0.f ? sp : 0.f;
    out[NA + 1] = 1.f / (1.f + __expf(-alpha[0]));
  }
}

// ---------------- masked logits: shuffle-free GEMV on transposed bf16 Wf --------
// one row per thread; 8x ushort8 coalesced loads; block max -> 1 atomic
__global__ __launch_bounds__(256) void k_logits(const float* __restrict__ g,
    const ushort* __restrict__ wfT8, const float* __restrict__ bf,
    const unsigned char* __restrict__ aflag, const int* __restrict__ src,
    const int* __restrict__ dst, float* __restrict__ logits,
    unsigned* __restrict__ gmax_key, int E, int NA, int NAp) {
  __shared__ float gs[64];
  __shared__ float wmax[4];
  int tid = threadIdx.x;
  if (tid < 64) gs[tid] = g[tid];
  __syncthreads();
  int r = blockIdx.x * 256 + tid;
  float val = -INFINITY;
  if (r < NA) {
    float acc = 0.f;
#pragma unroll
    for (int k8 = 0; k8 < 8; ++k8) {
      short8 w = *(const short8*)(const void*)(wfT8 + ((size_t)k8 * NAp + r) * 8);
#pragma unroll
      for (int j = 0; j < 8; ++j)
        acc += b2f((unsigned short)w[j]) * gs[k8 * 8 + j];
    }
    bool keep = (!aflag[r]) && (r >= E || src[r] != dst[r]);
    val = keep ? (acc + bf[r]) : -INFINITY;
    logits[r] = val;
  }
  float mv = wred_max(val);
  if ((tid & 63) == 0) wmax[tid >> 6] = mv;
  __syncthreads();
  if (tid == 0) {
    float m = fmaxf(fmaxf(wmax[0], wmax[1]), fmaxf(wmax[2], wmax[3]));
    atomicMax(gmax_key, f2key(m));
  }
}

// ---------------- exp pass: float4, 1 atomic/block ----------------
__global__ __launch_bounds__(256) void k_exp(float* __restrict__ logits,
    const unsigned* __restrict__ gmax_key, float* __restrict__ gsum, int NA) {
  __shared__ float wsum[4];
  int i = (blockIdx.x * 256 + threadIdx.x) * 4;
  float gmax = key2f(*gmax_key);
  float s = 0.f;
  if (i < NA) {
    float4 v = *(const float4*)(logits + i);
    float4 e;
    e.x = (i + 0 < NA && v.x != -INFINITY) ? __expf(v.x - gmax) : 0.f;
    e.y = (i + 1 < NA && v.y != -INFINITY) ? __expf(v.y - gmax) : 0.f;
    e.z = (i + 2 < NA && v.z != -INFINITY) ? __expf(v.z - gmax) : 0.f;
    e.w = (i + 3 < NA && v.w != -INFINITY) ? __expf(v.w - gmax) : 0.f;
    *(float4*)(logits + i) = e;
    s = e.x + e.y + e.z + e.w;
  }
  s = wred_sum(s);
  if ((threadIdx.x & 63) == 0) wsum[threadIdx.x >> 6] = s;
  __syncthreads();
  if (threadIdx.x == 0)
    atomicAdd(gsum, wsum[0] + wsum[1] + wsum[2] + wsum[3]);
}

__global__ __launch_bounds__(256) void k_norm(const float* __restrict__ logits,
    const float* __restrict__ gsum, float* __restrict__ out, int NA) {
  int i = (blockIdx.x * 256 + threadIdx.x) * 4;
  if (i >= NA) return;
  float inv = 1.f / (*gsum);
  if (i + 3 < NA) {
    float4 v = *(const float4*)(logits + i);
    float4 o;
    o.x = v.x * inv; o.y = v.y * inv; o.z = v.z * inv; o.w = v.w * inv;
    *(float4*)(out + i) = o;
  } else {
    for (int j = i; j < NA; ++j) out[j] = logits[j] * inv;
  }
}

// ---------------- launch ----------------
extern "C" void kernel_launch(void* const* d_in, const int* in_sizes, int n_in,
                              void* d_out, int out_size, void* d_ws, size_t ws_size,
                              hipStream_t stream) {
  const float* x      = (const float*)d_in[0];
  const int*   eidx   = (const int*)d_in[1];
  const float* eattr  = (const float*)d_in[2];
  const int*   actions= (const int*)d_in[3];
  const float* Wl1 = (const float*)d_in[4];
  const float* bl1 = (const float*)d_in[5];
  const float* Wr1 = (const float*)d_in[6];
  const float* br1 = (const float*)d_in[7];
  const float* We1 = (const float*)d_in[8];
  const float* att1= (const float*)d_in[9];
  const float* bias1=(const float*)d_in[10];
  const float* Wl2 = (const float*)d_in[11];
  const float* bl2 = (const float*)d_in[12];
  const float* Wr2 = (const float*)d_in[13];
  const float* br2 = (const float*)d_in[14];
  const float* We2 = (const float*)d_in[15];
  const float* att2= (const float*)d_in[16];
  const float* bias2=(const float*)d_in[17];
  const float* Wf  = (const float*)d_in[18];
  const float* bf  = (const float*)d_in[19];
  const float* Wp  = (const float*)d_in[20];
  const float* bp  = (const float*)d_in[21];
  const float* alpha=(const float*)d_in[22];

  const int F = 128;
  const int N = in_sizes[0] / F;       // 20000
  const int E = in_sizes[2];           // 400000
  const int E2 = E + N;
  const int NA = E + 1;
  const int NAp = ((NA + 63) / 64) * 64;
  const int n_act = in_sizes[3];
  const int* src = eidx;
  const int* dst = eidx + E;
  const int hid = 64;

  float* ws = (float*)d_ws;
  size_t p = 0;
  int*      cnt_i    = (int*)(ws + p);      p += (size_t)N;
  float*    sum_ea   = ws + p;              p += (size_t)N;
  float*    g_sum    = ws + p;              p += 64;
  unsigned* gmax_key = (unsigned*)(ws + p); p += 64;
  float*    gsum     = ws + p;              p += 64;
  unsigned char* aflag = (unsigned char*)(ws + p); p += ((size_t)NA + 3) / 4;
  size_t zero_bytes = p * sizeof(float);    // one memset covers all of the above
  float*    g        = ws + p;              p += 64;
  float*    mean_ea  = ws + p;              p += (size_t)N;
  int*      row_st   = (int*)(ws + p);      p += (size_t)N + 64;
  int*      cursor   = (int*)(ws + p);      p += (size_t)N;
  int*      srcp     = (int*)(ws + p);      p += (size_t)E2;
  float*    eap      = ws + p;              p += (size_t)E2;
  float*    logits   = ws + p;              p += (size_t)NA + 64;
  p = (p + 3) & ~(size_t)3;                 // 16B align for bf16 region
  float*    h2       = ws + p;              p += (size_t)N * hid;
  ushort* ub = (ushort*)(ws + p);
  size_t q = 0;
  ushort* xb   = ub + q; q += (size_t)N * F;        // x bf16
  ushort* wl1b = ub + q; q += (size_t)256 * 128;
  ushort* wr1b = ub + q; q += (size_t)256 * 128;
  ushort* wl2b = ub + q; q += (size_t)64 * 256;
  ushort* wr2b = ub + q; q += (size_t)64 * 256;
  ushort* wfT8 = ub + q; q += (size_t)64 * NAp;     // transposed Wf bf16
  ushort* xl1b = ub + q; q += (size_t)N * 256;
  ushort* xr1b = ub + q; q += (size_t)N * 256;
  ushort* h1b  = ub + q; q += (size_t)N * 256;
  ushort* xl2b = ub + q; q += (size_t)N * 64;
  ushort* xr2b = ub + q; q += (size_t)N * 64;

  float* out = (float*)d_out;

  hipMemsetAsync(d_ws, 0, zero_bytes, stream);

  // casts: x + 4 weight matrices -> bf16
  {
    int n0 = N * F, n1 = 256 * 128, n2 = 256 * 128, n3 = 64 * 256, n4 = 64 * 256;
    int tot4 = (n0 + n1 + n2 + n3 + n4) / 4;
    k_cast5<<<(tot4 + 255) / 256, 256, 0, stream>>>(
        x, xb, n0, Wl1, wl1b, n1, Wr1, wr1b, n2, Wl2, wl2b, n3, Wr2, wr2b, n4);
  }
  // Wf transpose-cast (reads rows [0,NAp) of Wf; NAp < 450000 so in-bounds)
  k_twf<<<NAp / 64, 256, 0, stream>>>(Wf, wfT8, NAp);

  // CSR build + self-loop edge attr
  k_count_ea<<<(E + 255) / 256, 256, 0, stream>>>(dst, eattr, cnt_i, sum_ea, E);
  k_scan<<<1, 1024, 0, stream>>>(cnt_i, sum_ea, mean_ea, row_st, cursor, N);
  k_scatter<<<(E2 + 255) / 256, 256, 0, stream>>>(dst, src, eattr, mean_ea,
                                                  cursor, srcp, eap, E, E2);

  // layer 1 projections (bf16 MFMA): xl1b, xr1b in one launch
  {
    dim3 g1((N + 63) / 64, 256 / 64, 2);
    k_gemm_mfma2<<<g1, 256, 0, stream>>>(xb, wl1b, bl1, xl1b, wr1b, br1, xr1b,
                                         N, 256, 128);
  }
  k_fused1<<<(N + 7) / 8, 256, 0, stream>>>(xl1b, xr1b, srcp, eap, row_st,
                                            We1, att1, bias1, h1b, N);

  // layer 2 projections from h1b: xl2b, xr2b in one launch
  {
    dim3 g2((N + 63) / 64, 1, 2);
    k_gemm_mfma2<<<g2, 256, 0, stream>>>(h1b, wl2b, bl2, xl2b, wr2b, br2, xr2b,
                                         N, 64, 256);
  }
  k_fused2<<<(N + 31) / 32, 256, 0, stream>>>(xl2b, xr2b, srcp, eap, row_st,
                                              We2, att2, bias2, h2, N);

  // head
  k_pool<<<128, 256, 0, stream>>>(h2, g_sum, actions, aflag, n_act, N);
  k_head<<<1, 64, 0, stream>>>(g_sum, Wp, bp, alpha, g, out, N, NA);
  k_logits<<<(NA + 255) / 256, 256, 0, stream>>>(g, wfT8, bf, aflag, src, dst,
                                                 logits, gmax_key, E, NA, NAp);
  int nb4 = (NA + 1023) / 1024;
  k_exp<<<nb4, 256, 0, stream>>>(logits, gmax_key, gsum, NA);
  k_norm<<<nb4, 256, 0, stream>>>(logits, gsum, out, NA);
}

// Round 9
// 279.038 us; speedup vs baseline: 1.2979x; 1.1492x over previous
//
#include <hip/hip_runtime.h>
#include <math.h>

typedef __attribute__((ext_vector_type(8))) short short8;
typedef __attribute__((ext_vector_type(4))) float f32x4;

// ---------------- helpers ----------------
__device__ __forceinline__ float wred_sum(float v) {
#pragma unroll
  for (int off = 32; off; off >>= 1) v += __shfl_xor(v, off, 64);
  return v;
}
__device__ __forceinline__ float wred_max(float v) {
#pragma unroll
  for (int off = 32; off; off >>= 1) v = fmaxf(v, __shfl_xor(v, off, 64));
  return v;
}
__device__ __forceinline__ unsigned f2key(float x) {
  unsigned b = __float_as_uint(x);
  return (b & 0x80000000u) ? ~b : (b | 0x80000000u);
}
__device__ __forceinline__ float key2f(unsigned k) {
  unsigned b = (k & 0x80000000u) ? (k & 0x7FFFFFFFu) : ~k;
  return __uint_as_float(b);
}
__device__ __forceinline__ float b2f(unsigned short u) {
  return __uint_as_float(((unsigned)u) << 16);
}
__device__ __forceinline__ unsigned short f2b(float f) {
  unsigned b = __float_as_uint(f);
  return (unsigned short)((b + 0x7FFFu + ((b >> 16) & 1u)) >> 16);
}

// ---------------- prep: bf16 casts + Wf transpose-cast + degree count ----------
// block ranges: [0,castB) cast5 | [castB,castB+twfB) twf | rest count_ea
__global__ __launch_bounds__(256) void k_prep(
    const float* __restrict__ s0, ushort* __restrict__ d0, int n0,
    const float* __restrict__ s1, ushort* __restrict__ d1, int n1,
    const float* __restrict__ s2, ushort* __restrict__ d2, int n2,
    const float* __restrict__ s3, ushort* __restrict__ d3, int n3,
    const float* __restrict__ s4, ushort* __restrict__ d4, int n4,
    const float* __restrict__ Wf, ushort* __restrict__ wfT8, int NAp,
    const int* __restrict__ dstv, const float* __restrict__ ea,
    int* __restrict__ cnt_i, float* __restrict__ sum_ea, int E,
    int castB, int twfB) {
  __shared__ ushort lds[64][68];
  int b = blockIdx.x, tid = threadIdx.x;
  if (b < castB) {
    int t = (b * 256 + tid) * 4;
    const float* s; ushort* d; int off = t;
    if (off < n0) { s = s0; d = d0; }
    else { off -= n0;
      if (off < n1) { s = s1; d = d1; }
      else { off -= n1;
        if (off < n2) { s = s2; d = d2; }
        else { off -= n2;
          if (off < n3) { s = s3; d = d3; }
          else { off -= n3;
            if (off < n4) { s = s4; d = d4; }
            else return; } } } }
    float4 v = *(const float4*)(s + off);
    ushort4 o;
    o.x = f2b(v.x); o.y = f2b(v.y); o.z = f2b(v.z); o.w = f2b(v.w);
    *(ushort4*)(d + off) = o;
    return;
  }
  if (b < castB + twfB) {
    int row0 = (b - castB) * 64;
    int r = tid >> 2, cg = tid & 3;
    const float* srcp = Wf + ((size_t)(row0 + r)) * 64 + cg * 16;
#pragma unroll
    for (int u = 0; u < 4; ++u) {
      float4 v = *(const float4*)(srcp + u * 4);
      int c = cg * 16 + u * 4;
      lds[r][c + 0] = f2b(v.x); lds[r][c + 1] = f2b(v.y);
      lds[r][c + 2] = f2b(v.z); lds[r][c + 3] = f2b(v.w);
    }
    __syncthreads();
    int k8 = tid >> 5, rg = tid & 31;
#pragma unroll
    for (int h = 0; h < 2; ++h) {
      int r2 = rg + h * 32;
      ushort4 wa = *(const ushort4*)(&lds[r2][k8 * 8]);
      ushort4 wb = *(const ushort4*)(&lds[r2][k8 * 8 + 4]);
      ushort* dp = wfT8 + ((size_t)k8 * NAp + row0 + r2) * 8;
      *(ushort4*)(dp) = wa;
      *(ushort4*)(dp + 4) = wb;
    }
    return;
  }
  int e = (b - castB - twfB) * 256 + tid;
  if (e >= E) return;
  int d = dstv[e];
  atomicAdd(&cnt_i[d], 1);
  atomicAdd(&sum_ea[d], ea[e]);
}

// ---------------- strip-mined block scan: row_st[N+1], cursor, mean_ea --------
__global__ __launch_bounds__(1024) void k_scan(const int* __restrict__ cnt_i,
    const float* __restrict__ sum_ea, float* __restrict__ mean_ea,
    int* __restrict__ row_st, int* __restrict__ cursor, int N) {
  __shared__ int ws[16];
  int tid = threadIdx.x;
  int lane = tid & 63, w = tid >> 6;
  int running = 0;
  for (int base = 0; base < N; base += 1024) {
    int i = base + tid;
    int c = 0;
    if (i < N) {
      int cc = cnt_i[i];
      c = cc + 1;
      mean_ea[i] = sum_ea[i] / fmaxf((float)cc, 1.0f);
    }
    int inc = c;
#pragma unroll
    for (int off = 1; off < 64; off <<= 1) {
      int u = __shfl_up(inc, off, 64);
      if (lane >= off) inc += u;
    }
    if (lane == 63) ws[w] = inc;
    __syncthreads();
    if (tid < 16) {
      int s = ws[tid];
#pragma unroll
      for (int off = 1; off < 16; off <<= 1) {
        int u = __shfl_up(s, off, 16);
        if (tid >= off) s += u;
      }
      ws[tid] = s;
    }
    __syncthreads();
    int woff = (w == 0) ? 0 : ws[w - 1];
    int total = ws[15];
    int ex = running + woff + (inc - c);
    if (i < N) { row_st[i] = ex; cursor[i] = ex; }
    running += total;
    __syncthreads();
  }
  if (tid == 0) row_st[N] = running;
}

// ---------------- layer-1 GEMMs (z=0,1) + scatter (z=2) in one launch ----------
__global__ __launch_bounds__(256) void k_gemm_scatter(const ushort* __restrict__ A,
    const ushort* __restrict__ W0, const float* __restrict__ b0, ushort* __restrict__ C0,
    const ushort* __restrict__ W1, const float* __restrict__ b1, ushort* __restrict__ C1,
    int M, int Nc, int K,
    const int* __restrict__ dstv, const int* __restrict__ srcv,
    const float* __restrict__ ea, const float* __restrict__ mean_ea,
    int* __restrict__ cursor, int* __restrict__ srcp, float* __restrict__ eap,
    int E, int E2) {
  int tid = threadIdx.x;
  if (blockIdx.z == 2) {
    int flat = blockIdx.x * gridDim.y + blockIdx.y;
    int stride = gridDim.x * gridDim.y * 256;
    for (int e = flat * 256 + tid; e < E2; e += stride) {
      int d, sn; float av;
      if (e < E) { d = dstv[e]; sn = srcv[e]; av = ea[e]; }
      else { d = e - E; sn = d; av = mean_ea[d]; }
      int pos = atomicAdd(&cursor[d], 1);
      srcp[pos] = sn;
      eap[pos] = av;
    }
    return;
  }
  const ushort* W = blockIdx.z ? W1 : W0;
  const float* bias = blockIdx.z ? b1 : b0;
  ushort* C = blockIdx.z ? C1 : C0;
  int wave = tid >> 6, lane = tid & 63;
  int m0 = blockIdx.x * 64 + wave * 16;
  int n0 = blockIdx.y * 64;
  int r = lane & 15, g = lane >> 4;
  f32x4 acc[4] = {};
  int am = min(m0 + r, M - 1);
  const ushort* Arow = A + (size_t)am * K + g * 8;
  const ushort* Wrow = W + (size_t)(n0 + r) * K + g * 8;
  for (int k0 = 0; k0 < K; k0 += 32) {
    short8 a = *(const short8*)(const void*)(Arow + k0);
#pragma unroll
    for (int c = 0; c < 4; ++c) {
      short8 b = *(const short8*)(const void*)(Wrow + (size_t)c * 16 * K + k0);
      acc[c] = __builtin_amdgcn_mfma_f32_16x16x32_bf16(a, b, acc[c], 0, 0, 0);
    }
  }
#pragma unroll
  for (int c = 0; c < 4; ++c) {
    int gn = n0 + c * 16 + r;
    float bv = bias[gn];
#pragma unroll
    for (int j = 0; j < 4; ++j) {
      int gm = m0 + g * 4 + j;
      if (gm < M) C[(size_t)gm * Nc + gn] = f2b(acc[c][j] + bv);
    }
  }
}

// ---------------- plain bf16 MFMA GEMM (layer 2) ----------------
__global__ __launch_bounds__(256) void k_gemm_mfma2(const ushort* __restrict__ A,
    const ushort* __restrict__ W0, const float* __restrict__ b0, ushort* __restrict__ C0,
    const ushort* __restrict__ W1, const float* __restrict__ b1, ushort* __restrict__ C1,
    int M, int Nc, int K) {
  const ushort* W = blockIdx.z ? W1 : W0;
  const float* bias = blockIdx.z ? b1 : b0;
  ushort* C = blockIdx.z ? C1 : C0;
  int wave = threadIdx.x >> 6, lane = threadIdx.x & 63;
  int m0 = blockIdx.x * 64 + wave * 16;
  int n0 = blockIdx.y * 64;
  int r = lane & 15, g = lane >> 4;
  f32x4 acc[4] = {};
  int am = min(m0 + r, M - 1);
  const ushort* Arow = A + (size_t)am * K + g * 8;
  const ushort* Wrow = W + (size_t)(n0 + r) * K + g * 8;
  for (int k0 = 0; k0 < K; k0 += 32) {
    short8 a = *(const short8*)(const void*)(Arow + k0);
#pragma unroll
    for (int c = 0; c < 4; ++c) {
      short8 b = *(const short8*)(const void*)(Wrow + (size_t)c * 16 * K + k0);
      acc[c] = __builtin_amdgcn_mfma_f32_16x16x32_bf16(a, b, acc[c], 0, 0, 0);
    }
  }
#pragma unroll
  for (int c = 0; c < 4; ++c) {
    int gn = n0 + c * 16 + r;
    float bv = bias[gn];
#pragma unroll
    for (int j = 0; j < 4; ++j) {
      int gm = m0 + g * 4 + j;
      if (gm < M) C[(size_t)gm * Nc + gn] = f2b(acc[c][j] + bv);
    }
  }
}

// ---------------- layer 1 fused: 32 lanes/node, 2 nodes/wave ----------------
__global__ __launch_bounds__(256) void k_fused1(const ushort* __restrict__ xl,
    const ushort* __restrict__ xr, const int* __restrict__ srcp,
    const float* __restrict__ eap, const int* __restrict__ row_st,
    const float* __restrict__ We, const float* __restrict__ att,
    const float* __restrict__ bias, ushort* __restrict__ out, int N) {
  int tid = threadIdx.x;
  int lane = tid & 63;
  int half = lane >> 5, l32 = lane & 31;
  int n = blockIdx.x * 8 + (tid >> 6) * 2 + half;
  if (n >= N) return;
  int c0 = l32 * 8;
  float4 Wa = *(const float4*)(We + c0), Wb = *(const float4*)(We + c0 + 4);
  float4 Aa = *(const float4*)(att + c0), Ab = *(const float4*)(att + c0 + 4);
  float Wev[8] = {Wa.x, Wa.y, Wa.z, Wa.w, Wb.x, Wb.y, Wb.z, Wb.w};
  float atv[8] = {Aa.x, Aa.y, Aa.z, Aa.w, Ab.x, Ab.y, Ab.z, Ab.w};
  short8 xru = *(const short8*)(const void*)(xr + (size_t)n * 256 + c0);
  float xrf[8];
#pragma unroll
  for (int j = 0; j < 8; ++j) xrf[j] = b2f((unsigned short)xru[j]);
  int a = row_st[n], b = row_st[n + 1];
  float m = -INFINITY, den = 0.f;
  float acc[8] = {};
  int sn_nx = srcp[a];
  float av_nx = eap[a];
  for (int i = a; i < b; ++i) {
    int sn = sn_nx;
    float av = av_nx;
    short8 xu = *(const short8*)(const void*)(xl + (size_t)sn * 256 + c0);
    if (i + 1 < b) { sn_nx = srcp[i + 1]; av_nx = eap[i + 1]; }
    float x[8];
    float t = 0.f;
#pragma unroll
    for (int j = 0; j < 8; ++j) {
      x[j] = b2f((unsigned short)xu[j]);
      float v = x[j] + xrf[j] + av * Wev[j];
      v = v > 0.f ? v : 0.2f * v;
      t += atv[j] * v;
    }
    t += __shfl_xor(t, 1, 8);
    t += __shfl_xor(t, 2, 8);
    t += __shfl_xor(t, 4, 8);
    if (t > m) {
      float sc = __expf(m - t);
      m = t; den *= sc;
#pragma unroll
      for (int j = 0; j < 8; ++j) acc[j] *= sc;
    }
    float ex = __expf(t - m);
    den += ex;
#pragma unroll
    for (int j = 0; j < 8; ++j) acc[j] += ex * x[j];
  }
  float inv = 1.f / (den + 1e-16f);
  float4 Ba = *(const float4*)(bias + c0), Bb = *(const float4*)(bias + c0 + 4);
  float bv[8] = {Ba.x, Ba.y, Ba.z, Ba.w, Bb.x, Bb.y, Bb.z, Bb.w};
  short8 o;
#pragma unroll
  for (int j = 0; j < 8; ++j) o[j] = (short)f2b(fmaxf(acc[j] * inv + bv[j], 0.f));
  *(short8*)(void*)(out + (size_t)n * 256 + c0) = o;
}

// ---------------- layer 2 fused + global mean pool (no h2 buffer) --------------
__global__ __launch_bounds__(256) void k_fused2(const ushort* __restrict__ xl,
    const ushort* __restrict__ xr, const int* __restrict__ srcp,
    const float* __restrict__ eap, const int* __restrict__ row_st,
    const float* __restrict__ We, const float* __restrict__ att,
    const float* __restrict__ bias, float* __restrict__ g_sum, int N) {
  __shared__ float gred[4][64];
  int tid = threadIdx.x;
  int lane = tid & 63, w = tid >> 6;
  int sub = lane >> 3, l8 = lane & 7;
  int n = blockIdx.x * 32 + w * 8 + sub;
  bool valid = n < N;
  int c0 = l8 * 8;
  float4 Wa = *(const float4*)(We + c0), Wb = *(const float4*)(We + c0 + 4);
  float4 Aa = *(const float4*)(att + c0), Ab = *(const float4*)(att + c0 + 4);
  float Wev[8] = {Wa.x, Wa.y, Wa.z, Wa.w, Wb.x, Wb.y, Wb.z, Wb.w};
  float atv[8] = {Aa.x, Aa.y, Aa.z, Aa.w, Ab.x, Ab.y, Ab.z, Ab.w};
  float xrf[8] = {};
  if (valid) {
    short8 xru = *(const short8*)(const void*)(xr + (size_t)n * 64 + c0);
#pragma unroll
    for (int j = 0; j < 8; ++j) xrf[j] = b2f((unsigned short)xru[j]);
  }
  int a = 0, b = 0;
  if (valid) { a = row_st[n]; b = row_st[n + 1]; }
  float m = -INFINITY, den = 0.f;
  float acc[8] = {};
  int sn_nx = valid ? srcp[a] : 0;
  float av_nx = valid ? eap[a] : 0.f;
  for (int i = a; i < b; ++i) {
    int sn = sn_nx;
    float av = av_nx;
    short8 xu = *(const short8*)(const void*)(xl + (size_t)sn * 64 + c0);
    if (i + 1 < b) { sn_nx = srcp[i + 1]; av_nx = eap[i + 1]; }
    float x[8];
    float t = 0.f;
#pragma unroll
    for (int j = 0; j < 8; ++j) {
      x[j] = b2f((unsigned short)xu[j]);
      float v = x[j] + xrf[j] + av * Wev[j];
      v = v > 0.f ? v : 0.2f * v;
      t += atv[j] * v;
    }
    t += __shfl_xor(t, 1, 8);
    t += __shfl_xor(t, 2, 8);
    t += __shfl_xor(t, 4, 8);
    if (t > m) {
      float sc = __expf(m - t);
      m = t; den *= sc;
#pragma unroll
      for (int j = 0; j < 8; ++j) acc[j] *= sc;
    }
    float ex = __expf(t - m);
    den += ex;
#pragma unroll
    for (int j = 0; j < 8; ++j) acc[j] += ex * x[j];
  }
  float inv = 1.f / (den + 1e-16f);
  float4 Ba = *(const float4*)(bias + c0), Bb = *(const float4*)(bias + c0 + 4);
  float bv[8] = {Ba.x, Ba.y, Ba.z, Ba.w, Bb.x, Bb.y, Bb.z, Bb.w};
  float vals[8];
#pragma unroll
  for (int j = 0; j < 8; ++j)
    vals[j] = valid ? fmaxf(acc[j] * inv + bv[j], 0.f) : 0.f;
  // reduce over the 8 subs within the wave (lanes differing in bits 3..5)
#pragma unroll
  for (int j = 0; j < 8; ++j) {
    float v = vals[j];
    v += __shfl_xor(v, 8, 64);
    v += __shfl_xor(v, 16, 64);
    v += __shfl_xor(v, 32, 64);
    vals[j] = v;
  }
  if (lane < 8) {
#pragma unroll
    for (int j = 0; j < 8; ++j) gred[w][lane * 8 + j] = vals[j];
  }
  __syncthreads();
  if (tid < 64)
    atomicAdd(&g_sum[tid], gred[0][tid] + gred[1][tid] + gred[2][tid] + gred[3][tid]);
}

// ---------------- masked logits + head (g, state potential, sigmoid) -----------
__global__ __launch_bounds__(256) void k_logits(const float* __restrict__ g_sum,
    const float* __restrict__ Wp, const float* __restrict__ bp,
    const float* __restrict__ alpha, const int* __restrict__ actions, int n_act,
    const ushort* __restrict__ wfT8, const float* __restrict__ bf,
    const unsigned char* __restrict__ aflag, const int* __restrict__ src,
    const int* __restrict__ dst, float* __restrict__ logits,
    unsigned* __restrict__ gmax_key, float* __restrict__ out,
    int E, int NA, int NAp, float invN) {
  __shared__ float gs[64];
  __shared__ float wmax[4];
  int tid = threadIdx.x;
  if (tid < 64) gs[tid] = g_sum[tid] * invN;
  __syncthreads();
  if (blockIdx.x == 0 && tid < 64) {
    float t = wred_sum(gs[tid] * Wp[tid]);
    if (tid == 0) {
      float sp = t + bp[0];
      out[NA] = sp > 0.f ? sp : 0.f;
      out[NA + 1] = 1.f / (1.f + __expf(-alpha[0]));
    }
  }
  int r = blockIdx.x * 256 + tid;
  float val = -INFINITY;
  if (r < NA) {
    float acc = 0.f;
#pragma unroll
    for (int k8 = 0; k8 < 8; ++k8) {
      short8 w = *(const short8*)(const void*)(wfT8 + ((size_t)k8 * NAp + r) * 8);
#pragma unroll
      for (int j = 0; j < 8; ++j)
        acc += b2f((unsigned short)w[j]) * gs[k8 * 8 + j];
    }
    bool keep = (!aflag[r]) && (r >= E || src[r] != dst[r]);
    val = keep ? (acc + bf[r]) : -INFINITY;
    logits[r] = val;
  }
  float mv = wred_max(val);
  if ((tid & 63) == 0) wmax[tid >> 6] = mv;
  __syncthreads();
  if (tid == 0) {
    float m = fmaxf(fmaxf(wmax[0], wmax[1]), fmaxf(wmax[2], wmax[3]));
    atomicMax(gmax_key, f2key(m));
  }
}

// ---------------- aflag scatter is tiny: fold into exp? needs ordering; keep in pool-less path
__global__ void k_aflag(const int* __restrict__ actions, unsigned char* __restrict__ aflag,
                        int n_act) {
  int i = threadIdx.x;
  if (i < n_act) aflag[actions[i]] = 1;
}

// ---------------- exp pass: float4, 1 atomic/block ----------------
__global__ __launch_bounds__(256) void k_exp(float* __restrict__ logits,
    const unsigned* __restrict__ gmax_key, float* __restrict__ gsum, int NA) {
  __shared__ float wsum[4];
  int i = (blockIdx.x * 256 + threadIdx.x) * 4;
  float gmax = key2f(*gmax_key);
  float s = 0.f;
  if (i < NA) {
    float4 v = *(const float4*)(logits + i);
    float4 e;
    e.x = (i + 0 < NA && v.x != -INFINITY) ? __expf(v.x - gmax) : 0.f;
    e.y = (i + 1 < NA && v.y != -INFINITY) ? __expf(v.y - gmax) : 0.f;
    e.z = (i + 2 < NA && v.z != -INFINITY) ? __expf(v.z - gmax) : 0.f;
    e.w = (i + 3 < NA && v.w != -INFINITY) ? __expf(v.w - gmax) : 0.f;
    *(float4*)(logits + i) = e;
    s = e.x + e.y + e.z + e.w;
  }
  s = wred_sum(s);
  if ((threadIdx.x & 63) == 0) wsum[threadIdx.x >> 6] = s;
  __syncthreads();
  if (threadIdx.x == 0)
    atomicAdd(gsum, wsum[0] + wsum[1] + wsum[2] + wsum[3]);
}

__global__ __launch_bounds__(256) void k_norm(const float* __restrict__ logits,
    const float* __restrict__ gsum, float* __restrict__ out, int NA) {
  int i = (blockIdx.x * 256 + threadIdx.x) * 4;
  if (i >= NA) return;
  float inv = 1.f / (*gsum);
  if (i + 3 < NA) {
    float4 v = *(const float4*)(logits + i);
    float4 o;
    o.x = v.x * inv; o.y = v.y * inv; o.z = v.z * inv; o.w = v.w * inv;
    *(float4*)(out + i) = o;
  } else {
    for (int j = i; j < NA; ++j) out[j] = logits[j] * inv;
  }
}

// ---------------- launch ----------------
extern "C" void kernel_launch(void* const* d_in, const int* in_sizes, int n_in,
                              void* d_out, int out_size, void* d_ws, size_t ws_size,
                              hipStream_t stream) {
  const float* x      = (const float*)d_in[0];
  const int*   eidx   = (const int*)d_in[1];
  const float* eattr  = (const float*)d_in[2];
  const int*   actions= (const int*)d_in[3];
  const float* Wl1 = (const float*)d_in[4];
  const float* bl1 = (const float*)d_in[5];
  const float* Wr1 = (const float*)d_in[6];
  const float* br1 = (const float*)d_in[7];
  const float* We1 = (const float*)d_in[8];
  const float* att1= (const float*)d_in[9];
  const float* bias1=(const float*)d_in[10];
  const float* Wl2 = (const float*)d_in[11];
  const float* bl2 = (const float*)d_in[12];
  const float* Wr2 = (const float*)d_in[13];
  const float* br2 = (const float*)d_in[14];
  const float* We2 = (const float*)d_in[15];
  const float* att2= (const float*)d_in[16];
  const float* bias2=(const float*)d_in[17];
  const float* Wf  = (const float*)d_in[18];
  const float* bf  = (const float*)d_in[19];
  const float* Wp  = (const float*)d_in[20];
  const float* bp  = (const float*)d_in[21];
  const float* alpha=(const float*)d_in[22];

  const int F = 128;
  const int N = in_sizes[0] / F;       // 20000
  const int E = in_sizes[2];           // 400000
  const int E2 = E + N;
  const int NA = E + 1;
  const int NAp = ((NA + 63) / 64) * 64;
  const int n_act = in_sizes[3];
  const int* src = eidx;
  const int* dst = eidx + E;

  float* ws = (float*)d_ws;
  size_t p = 0;
  int*      cnt_i    = (int*)(ws + p);      p += (size_t)N;
  float*    sum_ea   = ws + p;              p += (size_t)N;
  float*    g_sum    = ws + p;              p += 64;
  unsigned* gmax_key = (unsigned*)(ws + p); p += 64;
  float*    gsum     = ws + p;              p += 64;
  unsigned char* aflag = (unsigned char*)(ws + p); p += ((size_t)NA + 3) / 4;
  size_t zero_bytes = p * sizeof(float);
  float*    mean_ea  = ws + p;              p += (size_t)N;
  int*      row_st   = (int*)(ws + p);      p += (size_t)N + 64;
  int*      cursor   = (int*)(ws + p);      p += (size_t)N;
  int*      srcp     = (int*)(ws + p);      p += (size_t)E2;
  float*    eap      = ws + p;              p += (size_t)E2;
  float*    logits   = ws + p;              p += (size_t)NA + 64;
  p = (p + 3) & ~(size_t)3;
  ushort* ub = (ushort*)(ws + p);
  size_t q = 0;
  ushort* xb   = ub + q; q += (size_t)N * F;
  ushort* wl1b = ub + q; q += (size_t)256 * 128;
  ushort* wr1b = ub + q; q += (size_t)256 * 128;
  ushort* wl2b = ub + q; q += (size_t)64 * 256;
  ushort* wr2b = ub + q; q += (size_t)64 * 256;
  ushort* wfT8 = ub + q; q += (size_t)64 * NAp;
  ushort* xl1b = ub + q; q += (size_t)N * 256;
  ushort* xr1b = ub + q; q += (size_t)N * 256;
  ushort* h1b  = ub + q; q += (size_t)N * 256;
  ushort* xl2b = ub + q; q += (size_t)N * 64;
  ushort* xr2b = ub + q; q += (size_t)N * 64;

  float* out = (float*)d_out;

  hipMemsetAsync(d_ws, 0, zero_bytes, stream);

  // prep: casts + Wf transpose + degree count, one launch
  {
    int n0 = N * F, n1 = 256 * 128, n2 = 256 * 128, n3 = 64 * 256, n4 = 64 * 256;
    int tot4 = (n0 + n1 + n2 + n3 + n4) / 4;
    int castB = (tot4 + 255) / 256;
    int twfB = NAp / 64;
    int cntB = (E + 255) / 256;
    k_prep<<<castB + twfB + cntB, 256, 0, stream>>>(
        x, xb, n0, Wl1, wl1b, n1, Wr1, wr1b, n2, Wl2, wl2b, n3, Wr2, wr2b, n4,
        Wf, wfT8, NAp, dst, eattr, cnt_i, sum_ea, E, castB, twfB);
  }

  k_scan<<<1, 1024, 0, stream>>>(cnt_i, sum_ea, mean_ea, row_st, cursor, N);

  // layer-1 GEMMs + CSR scatter in one launch
  {
    dim3 g1((N + 63) / 64, 4, 3);
    k_gemm_scatter<<<g1, 256, 0, stream>>>(xb, wl1b, bl1, xl1b, wr1b, br1, xr1b,
                                           N, 256, 128,
                                           dst, src, eattr, mean_ea, cursor,
                                           srcp, eap, E, E2);
  }
  k_fused1<<<(N + 7) / 8, 256, 0, stream>>>(xl1b, xr1b, srcp, eap, row_st,
                                            We1, att1, bias1, h1b, N);
  {
    dim3 g2((N + 63) / 64, 1, 2);
    k_gemm_mfma2<<<g2, 256, 0, stream>>>(h1b, wl2b, bl2, xl2b, wr2b, br2, xr2b,
                                         N, 64, 256);
  }
  k_fused2<<<(N + 31) / 32, 256, 0, stream>>>(xl2b, xr2b, srcp, eap, row_st,
                                              We2, att2, bias2, g_sum, N);

  k_aflag<<<1, 128, 0, stream>>>(actions, aflag, n_act);
  k_logits<<<(NA + 255) / 256, 256, 0, stream>>>(
      g_sum, Wp, bp, alpha, actions, n_act, wfT8, bf, aflag, src, dst,
      logits, gmax_key, out, E, NA, NAp, 1.0f / (float)N);
  int nb4 = (NA + 1023) / 1024;
  k_exp<<<nb4, 256, 0, stream>>>(logits, gmax_key, gsum, NA);
  k_norm<<<nb4, 256, 0, stream>>>(logits, gsum, out, NA);
}

// Round 10
// 271.972 us; speedup vs baseline: 1.3316x; 1.0260x over previous
//
#include <hip/hip_runtime.h>
#include <math.h>

typedef __attribute__((ext_vector_type(8))) short short8;
typedef __attribute__((ext_vector_type(4))) float f32x4;

// ---------------- helpers ----------------
__device__ __forceinline__ float wred_sum(float v) {
#pragma unroll
  for (int off = 32; off; off >>= 1) v += __shfl_xor(v, off, 64);
  return v;
}
__device__ __forceinline__ float wred_max(float v) {
#pragma unroll
  for (int off = 32; off; off >>= 1) v = fmaxf(v, __shfl_xor(v, off, 64));
  return v;
}
__device__ __forceinline__ unsigned f2key(float x) {
  unsigned b = __float_as_uint(x);
  return (b & 0x80000000u) ? ~b : (b | 0x80000000u);
}
__device__ __forceinline__ float key2f(unsigned k) {
  unsigned b = (k & 0x80000000u) ? (k & 0x7FFFFFFFu) : ~k;
  return __uint_as_float(b);
}
__device__ __forceinline__ float b2f(unsigned short u) {
  return __uint_as_float(((unsigned)u) << 16);
}
__device__ __forceinline__ unsigned short f2b(float f) {
  unsigned b = __float_as_uint(f);
  return (unsigned short)((b + 0x7FFFu + ((b >> 16) & 1u)) >> 16);
}

// ---------------- prep: bf16 casts + degree count + aflag scatter ----------
// block ranges: [0,castB) cast5 | rest count_ea; block 0 also scatters aflag
__global__ __launch_bounds__(256) void k_prep(
    const float* __restrict__ s0, ushort* __restrict__ d0, int n0,
    const float* __restrict__ s1, ushort* __restrict__ d1, int n1,
    const float* __restrict__ s2, ushort* __restrict__ d2, int n2,
    const float* __restrict__ s3, ushort* __restrict__ d3, int n3,
    const float* __restrict__ s4, ushort* __restrict__ d4, int n4,
    const int* __restrict__ dstv, const float* __restrict__ ea,
    int* __restrict__ cnt_i, float* __restrict__ sum_ea, int E,
    const int* __restrict__ actions, unsigned char* __restrict__ aflag,
    int n_act, int castB) {
  int b = blockIdx.x, tid = threadIdx.x;
  if (b == 0 && tid < n_act) aflag[actions[tid]] = 1;
  if (b < castB) {
    int t = (b * 256 + tid) * 4;
    const float* s; ushort* d; int off = t;
    if (off < n0) { s = s0; d = d0; }
    else { off -= n0;
      if (off < n1) { s = s1; d = d1; }
      else { off -= n1;
        if (off < n2) { s = s2; d = d2; }
        else { off -= n2;
          if (off < n3) { s = s3; d = d3; }
          else { off -= n3;
            if (off < n4) { s = s4; d = d4; }
            else return; } } } }
    float4 v = *(const float4*)(s + off);
    ushort4 o;
    o.x = f2b(v.x); o.y = f2b(v.y); o.z = f2b(v.z); o.w = f2b(v.w);
    *(ushort4*)(d + off) = o;
    return;
  }
  int e = (b - castB) * 256 + tid;
  if (e >= E) return;
  int d = dstv[e];
  atomicAdd(&cnt_i[d], 1);
  atomicAdd(&sum_ea[d], ea[e]);
}

// ---------------- strip-mined block scan: row_st[N+1], cursor, mean_ea --------
__global__ __launch_bounds__(1024) void k_scan(const int* __restrict__ cnt_i,
    const float* __restrict__ sum_ea, float* __restrict__ mean_ea,
    int* __restrict__ row_st, int* __restrict__ cursor, int N) {
  __shared__ int ws[16];
  int tid = threadIdx.x;
  int lane = tid & 63, w = tid >> 6;
  int running = 0;
  for (int base = 0; base < N; base += 1024) {
    int i = base + tid;
    int c = 0;
    if (i < N) {
      int cc = cnt_i[i];
      c = cc + 1;
      mean_ea[i] = sum_ea[i] / fmaxf((float)cc, 1.0f);
    }
    int inc = c;
#pragma unroll
    for (int off = 1; off < 64; off <<= 1) {
      int u = __shfl_up(inc, off, 64);
      if (lane >= off) inc += u;
    }
    if (lane == 63) ws[w] = inc;
    __syncthreads();
    if (tid < 16) {
      int s = ws[tid];
#pragma unroll
      for (int off = 1; off < 16; off <<= 1) {
        int u = __shfl_up(s, off, 16);
        if (tid >= off) s += u;
      }
      ws[tid] = s;
    }
    __syncthreads();
    int woff = (w == 0) ? 0 : ws[w - 1];
    int total = ws[15];
    int ex = running + woff + (inc - c);
    if (i < N) { row_st[i] = ex; cursor[i] = ex; }
    running += total;
    __syncthreads();
  }
  if (tid == 0) row_st[N] = running;
}

// ---------------- layer-1 GEMMs (z=0,1) + scatter (z=2) in one launch ----------
__global__ __launch_bounds__(256) void k_gemm_scatter(const ushort* __restrict__ A,
    const ushort* __restrict__ W0, const float* __restrict__ b0, ushort* __restrict__ C0,
    const ushort* __restrict__ W1, const float* __restrict__ b1, ushort* __restrict__ C1,
    int M, int Nc, int K,
    const int* __restrict__ dstv, const int* __restrict__ srcv,
    const float* __restrict__ ea, const float* __restrict__ mean_ea,
    int* __restrict__ cursor, int* __restrict__ srcp, float* __restrict__ eap,
    int E, int E2) {
  int tid = threadIdx.x;
  if (blockIdx.z == 2) {
    int flat = blockIdx.x * gridDim.y + blockIdx.y;
    int stride = gridDim.x * gridDim.y * 256;
    for (int e = flat * 256 + tid; e < E2; e += stride) {
      int d, sn; float av;
      if (e < E) { d = dstv[e]; sn = srcv[e]; av = ea[e]; }
      else { d = e - E; sn = d; av = mean_ea[d]; }
      int pos = atomicAdd(&cursor[d], 1);
      srcp[pos] = sn;
      eap[pos] = av;
    }
    return;
  }
  const ushort* W = blockIdx.z ? W1 : W0;
  const float* bias = blockIdx.z ? b1 : b0;
  ushort* C = blockIdx.z ? C1 : C0;
  int wave = tid >> 6, lane = tid & 63;
  int m0 = blockIdx.x * 64 + wave * 16;
  int n0 = blockIdx.y * 64;
  int r = lane & 15, g = lane >> 4;
  f32x4 acc[4] = {};
  int am = min(m0 + r, M - 1);
  const ushort* Arow = A + (size_t)am * K + g * 8;
  const ushort* Wrow = W + (size_t)(n0 + r) * K + g * 8;
  for (int k0 = 0; k0 < K; k0 += 32) {
    short8 a = *(const short8*)(const void*)(Arow + k0);
#pragma unroll
    for (int c = 0; c < 4; ++c) {
      short8 b = *(const short8*)(const void*)(Wrow + (size_t)c * 16 * K + k0);
      acc[c] = __builtin_amdgcn_mfma_f32_16x16x32_bf16(a, b, acc[c], 0, 0, 0);
    }
  }
#pragma unroll
  for (int c = 0; c < 4; ++c) {
    int gn = n0 + c * 16 + r;
    float bv = bias[gn];
#pragma unroll
    for (int j = 0; j < 4; ++j) {
      int gm = m0 + g * 4 + j;
      if (gm < M) C[(size_t)gm * Nc + gn] = f2b(acc[c][j] + bv);
    }
  }
}

// ---------------- plain bf16 MFMA GEMM (layer 2) ----------------
__global__ __launch_bounds__(256) void k_gemm_mfma2(const ushort* __restrict__ A,
    const ushort* __restrict__ W0, const float* __restrict__ b0, ushort* __restrict__ C0,
    const ushort* __restrict__ W1, const float* __restrict__ b1, ushort* __restrict__ C1,
    int M, int Nc, int K) {
  const ushort* W = blockIdx.z ? W1 : W0;
  const float* bias = blockIdx.z ? b1 : b0;
  ushort* C = blockIdx.z ? C1 : C0;
  int wave = threadIdx.x >> 6, lane = threadIdx.x & 63;
  int m0 = blockIdx.x * 64 + wave * 16;
  int n0 = blockIdx.y * 64;
  int r = lane & 15, g = lane >> 4;
  f32x4 acc[4] = {};
  int am = min(m0 + r, M - 1);
  const ushort* Arow = A + (size_t)am * K + g * 8;
  const ushort* Wrow = W + (size_t)(n0 + r) * K + g * 8;
  for (int k0 = 0; k0 < K; k0 += 32) {
    short8 a = *(const short8*)(const void*)(Arow + k0);
#pragma unroll
    for (int c = 0; c < 4; ++c) {
      short8 b = *(const short8*)(const void*)(Wrow + (size_t)c * 16 * K + k0);
      acc[c] = __builtin_amdgcn_mfma_f32_16x16x32_bf16(a, b, acc[c], 0, 0, 0);
    }
  }
#pragma unroll
  for (int c = 0; c < 4; ++c) {
    int gn = n0 + c * 16 + r;
    float bv = bias[gn];
#pragma unroll
    for (int j = 0; j < 4; ++j) {
      int gm = m0 + g * 4 + j;
      if (gm < M) C[(size_t)gm * Nc + gn] = f2b(acc[c][j] + bv);
    }
  }
}

// ---------------- layer 1 fused: 32 lanes/node, 2 nodes/wave ----------------
__global__ __launch_bounds__(256) void k_fused1(const ushort* __restrict__ xl,
    const ushort* __restrict__ xr, const int* __restrict__ srcp,
    const float* __restrict__ eap, const int* __restrict__ row_st,
    const float* __restrict__ We, const float* __restrict__ att,
    const float* __restrict__ bias, ushort* __restrict__ out, int N) {
  int tid = threadIdx.x;
  int lane = tid & 63;
  int half = lane >> 5, l32 = lane & 31;
  int n = blockIdx.x * 8 + (tid >> 6) * 2 + half;
  if (n >= N) return;
  int c0 = l32 * 8;
  float4 Wa = *(const float4*)(We + c0), Wb = *(const float4*)(We + c0 + 4);
  float4 Aa = *(const float4*)(att + c0), Ab = *(const float4*)(att + c0 + 4);
  float Wev[8] = {Wa.x, Wa.y, Wa.z, Wa.w, Wb.x, Wb.y, Wb.z, Wb.w};
  float atv[8] = {Aa.x, Aa.y, Aa.z, Aa.w, Ab.x, Ab.y, Ab.z, Ab.w};
  short8 xru = *(const short8*)(const void*)(xr + (size_t)n * 256 + c0);
  float xrf[8];
#pragma unroll
  for (int j = 0; j < 8; ++j) xrf[j] = b2f((unsigned short)xru[j]);
  int a = row_st[n], b = row_st[n + 1];
  float m = -INFINITY, den = 0.f;
  float acc[8] = {};
  int sn_nx = srcp[a];
  float av_nx = eap[a];
  for (int i = a; i < b; ++i) {
    int sn = sn_nx;
    float av = av_nx;
    short8 xu = *(const short8*)(const void*)(xl + (size_t)sn * 256 + c0);
    if (i + 1 < b) { sn_nx = srcp[i + 1]; av_nx = eap[i + 1]; }
    float x[8];
    float t = 0.f;
#pragma unroll
    for (int j = 0; j < 8; ++j) {
      x[j] = b2f((unsigned short)xu[j]);
      float v = x[j] + xrf[j] + av * Wev[j];
      v = v > 0.f ? v : 0.2f * v;
      t += atv[j] * v;
    }
    t += __shfl_xor(t, 1, 8);
    t += __shfl_xor(t, 2, 8);
    t += __shfl_xor(t, 4, 8);
    if (t > m) {
      float sc = __expf(m - t);
      m = t; den *= sc;
#pragma unroll
      for (int j = 0; j < 8; ++j) acc[j] *= sc;
    }
    float ex = __expf(t - m);
    den += ex;
#pragma unroll
    for (int j = 0; j < 8; ++j) acc[j] += ex * x[j];
  }
  float inv = 1.f / (den + 1e-16f);
  float4 Ba = *(const float4*)(bias + c0), Bb = *(const float4*)(bias + c0 + 4);
  float bv[8] = {Ba.x, Ba.y, Ba.z, Ba.w, Bb.x, Bb.y, Bb.z, Bb.w};
  short8 o;
#pragma unroll
  for (int j = 0; j < 8; ++j) o[j] = (short)f2b(fmaxf(acc[j] * inv + bv[j], 0.f));
  *(short8*)(void*)(out + (size_t)n * 256 + c0) = o;
}

// ---------------- layer 2 fused + global mean pool (no h2 buffer) --------------
__global__ __launch_bounds__(256) void k_fused2(const ushort* __restrict__ xl,
    const ushort* __restrict__ xr, const int* __restrict__ srcp,
    const float* __restrict__ eap, const int* __restrict__ row_st,
    const float* __restrict__ We, const float* __restrict__ att,
    const float* __restrict__ bias, float* __restrict__ g_sum, int N) {
  __shared__ float gred[4][64];
  int tid = threadIdx.x;
  int lane = tid & 63, w = tid >> 6;
  int sub = lane >> 3, l8 = lane & 7;
  int n = blockIdx.x * 32 + w * 8 + sub;
  bool valid = n < N;
  int c0 = l8 * 8;
  float4 Wa = *(const float4*)(We + c0), Wb = *(const float4*)(We + c0 + 4);
  float4 Aa = *(const float4*)(att + c0), Ab = *(const float4*)(att + c0 + 4);
  float Wev[8] = {Wa.x, Wa.y, Wa.z, Wa.w, Wb.x, Wb.y, Wb.z, Wb.w};
  float atv[8] = {Aa.x, Aa.y, Aa.z, Aa.w, Ab.x, Ab.y, Ab.z, Ab.w};
  float xrf[8] = {};
  if (valid) {
    short8 xru = *(const short8*)(const void*)(xr + (size_t)n * 64 + c0);
#pragma unroll
    for (int j = 0; j < 8; ++j) xrf[j] = b2f((unsigned short)xru[j]);
  }
  int a = 0, b = 0;
  if (valid) { a = row_st[n]; b = row_st[n + 1]; }
  float m = -INFINITY, den = 0.f;
  float acc[8] = {};
  int sn_nx = valid ? srcp[a] : 0;
  float av_nx = valid ? eap[a] : 0.f;
  for (int i = a; i < b; ++i) {
    int sn = sn_nx;
    float av = av_nx;
    short8 xu = *(const short8*)(const void*)(xl + (size_t)sn * 64 + c0);
    if (i + 1 < b) { sn_nx = srcp[i + 1]; av_nx = eap[i + 1]; }
    float x[8];
    float t = 0.f;
#pragma unroll
    for (int j = 0; j < 8; ++j) {
      x[j] = b2f((unsigned short)xu[j]);
      float v = x[j] + xrf[j] + av * Wev[j];
      v = v > 0.f ? v : 0.2f * v;
      t += atv[j] * v;
    }
    t += __shfl_xor(t, 1, 8);
    t += __shfl_xor(t, 2, 8);
    t += __shfl_xor(t, 4, 8);
    if (t > m) {
      float sc = __expf(m - t);
      m = t; den *= sc;
#pragma unroll
      for (int j = 0; j < 8; ++j) acc[j] *= sc;
    }
    float ex = __expf(t - m);
    den += ex;
#pragma unroll
    for (int j = 0; j < 8; ++j) acc[j] += ex * x[j];
  }
  float inv = 1.f / (den + 1e-16f);
  float4 Ba = *(const float4*)(bias + c0), Bb = *(const float4*)(bias + c0 + 4);
  float bv[8] = {Ba.x, Ba.y, Ba.z, Ba.w, Bb.x, Bb.y, Bb.z, Bb.w};
  float vals[8];
#pragma unroll
  for (int j = 0; j < 8; ++j)
    vals[j] = valid ? fmaxf(acc[j] * inv + bv[j], 0.f) : 0.f;
#pragma unroll
  for (int j = 0; j < 8; ++j) {
    float v = vals[j];
    v += __shfl_xor(v, 8, 64);
    v += __shfl_xor(v, 16, 64);
    v += __shfl_xor(v, 32, 64);
    vals[j] = v;
  }
  if (lane < 8) {
#pragma unroll
    for (int j = 0; j < 8; ++j) gred[w][lane * 8 + j] = vals[j];
  }
  __syncthreads();
  if (tid < 64)
    atomicAdd(&g_sum[tid], gred[0][tid] + gred[1][tid] + gred[2][tid] + gred[3][tid]);
}

// ---------------- masked logits (f32 Wf direct, 4 lanes/row) + head -----------
__global__ __launch_bounds__(256) void k_logits(const float* __restrict__ g_sum,
    const float* __restrict__ Wp, const float* __restrict__ bp,
    const float* __restrict__ alpha,
    const float* __restrict__ Wf, const float* __restrict__ bf,
    const unsigned char* __restrict__ aflag, const int* __restrict__ src,
    const int* __restrict__ dst, float* __restrict__ logits,
    unsigned* __restrict__ gmax_key, float* __restrict__ out,
    int E, int NA, float invN) {
  __shared__ float gs[64];
  __shared__ float wmax[4];
  int tid = threadIdx.x;
  if (tid < 64) gs[tid] = g_sum[tid] * invN;
  __syncthreads();
  if (blockIdx.x == 0 && tid < 64) {
    float t = wred_sum(gs[tid] * Wp[tid]);
    if (tid == 0) {
      float sp = t + bp[0];
      out[NA] = sp > 0.f ? sp : 0.f;
      out[NA + 1] = 1.f / (1.f + __expf(-alpha[0]));
    }
  }
  int j0 = tid & 3;
  int row = blockIdx.x * 64 + (tid >> 2);
  float val = -INFINITY;
  if (row < NA) {
    const float4* wr = (const float4*)(Wf + (size_t)row * 64);
    const float4* g4 = (const float4*)gs;
    float acc = 0.f;
#pragma unroll
    for (int u = 0; u < 4; ++u) {
      float4 w = wr[j0 + u * 4];
      float4 gv = g4[j0 + u * 4];
      acc += w.x * gv.x + w.y * gv.y + w.z * gv.z + w.w * gv.w;
    }
    acc += __shfl_xor(acc, 1, 4);
    acc += __shfl_xor(acc, 2, 4);
    if (j0 == 0) {
      bool keep = (!aflag[row]) && (row >= E || src[row] != dst[row]);
      val = keep ? (acc + bf[row]) : -INFINITY;
      logits[row] = val;
    }
  }
  float mv = wred_max(val);
  if ((tid & 63) == 0) wmax[tid >> 6] = mv;
  __syncthreads();
  if (tid == 0) {
    float m = fmaxf(fmaxf(wmax[0], wmax[1]), fmaxf(wmax[2], wmax[3]));
    atomicMax(&gmax_key[blockIdx.x & 63], f2key(m));  // 64-way spread
  }
}

// ---------------- exp pass: reduce 64 max-slots in-wave, 1 atomic/block --------
__global__ __launch_bounds__(256) void k_exp(float* __restrict__ logits,
    const unsigned* __restrict__ gmax_key, float* __restrict__ gsum, int NA) {
  __shared__ float wsum[4];
  int tid = threadIdx.x;
  float gmax = key2f(gmax_key[tid & 63]);
  gmax = wred_max(gmax);
  int i = (blockIdx.x * 256 + tid) * 4;
  float s = 0.f;
  if (i < NA) {
    float4 v = *(const float4*)(logits + i);
    float4 e;
    e.x = (i + 0 < NA && v.x != -INFINITY) ? __expf(v.x - gmax) : 0.f;
    e.y = (i + 1 < NA && v.y != -INFINITY) ? __expf(v.y - gmax) : 0.f;
    e.z = (i + 2 < NA && v.z != -INFINITY) ? __expf(v.z - gmax) : 0.f;
    e.w = (i + 3 < NA && v.w != -INFINITY) ? __expf(v.w - gmax) : 0.f;
    *(float4*)(logits + i) = e;
    s = e.x + e.y + e.z + e.w;
  }
  s = wred_sum(s);
  if ((tid & 63) == 0) wsum[tid >> 6] = s;
  __syncthreads();
  if (tid == 0)
    atomicAdd(gsum, wsum[0] + wsum[1] + wsum[2] + wsum[3]);
}

__global__ __launch_bounds__(256) void k_norm(const float* __restrict__ logits,
    const float* __restrict__ gsum, float* __restrict__ out, int NA) {
  int i = (blockIdx.x * 256 + threadIdx.x) * 4;
  if (i >= NA) return;
  float inv = 1.f / (*gsum);
  if (i + 3 < NA) {
    float4 v = *(const float4*)(logits + i);
    float4 o;
    o.x = v.x * inv; o.y = v.y * inv; o.z = v.z * inv; o.w = v.w * inv;
    *(float4*)(out + i) = o;
  } else {
    for (int j = i; j < NA; ++j) out[j] = logits[j] * inv;
  }
}

// ---------------- launch ----------------
extern "C" void kernel_launch(void* const* d_in, const int* in_sizes, int n_in,
                              void* d_out, int out_size, void* d_ws, size_t ws_size,
                              hipStream_t stream) {
  const float* x      = (const float*)d_in[0];
  const int*   eidx   = (const int*)d_in[1];
  const float* eattr  = (const float*)d_in[2];
  const int*   actions= (const int*)d_in[3];
  const float* Wl1 = (const float*)d_in[4];
  const float* bl1 = (const float*)d_in[5];
  const float* Wr1 = (const float*)d_in[6];
  const float* br1 = (const float*)d_in[7];
  const float* We1 = (const float*)d_in[8];
  const float* att1= (const float*)d_in[9];
  const float* bias1=(const float*)d_in[10];
  const float* Wl2 = (const float*)d_in[11];
  const float* bl2 = (const float*)d_in[12];
  const float* Wr2 = (const float*)d_in[13];
  const float* br2 = (const float*)d_in[14];
  const float* We2 = (const float*)d_in[15];
  const float* att2= (const float*)d_in[16];
  const float* bias2=(const float*)d_in[17];
  const float* Wf  = (const float*)d_in[18];
  const float* bf  = (const float*)d_in[19];
  const float* Wp  = (const float*)d_in[20];
  const float* bp  = (const float*)d_in[21];
  const float* alpha=(const float*)d_in[22];

  const int F = 128;
  const int N = in_sizes[0] / F;       // 20000
  const int E = in_sizes[2];           // 400000
  const int E2 = E + N;
  const int NA = E + 1;
  const int n_act = in_sizes[3];
  const int* src = eidx;
  const int* dst = eidx + E;

  float* ws = (float*)d_ws;
  size_t p = 0;
  int*      cnt_i    = (int*)(ws + p);      p += (size_t)N;
  float*    sum_ea   = ws + p;              p += (size_t)N;
  float*    g_sum    = ws + p;              p += 64;
  unsigned* gmax_key = (unsigned*)(ws + p); p += 64;
  float*    gsum     = ws + p;              p += 64;
  unsigned char* aflag = (unsigned char*)(ws + p); p += ((size_t)NA + 3) / 4;
  size_t zero_bytes = p * sizeof(float);
  float*    mean_ea  = ws + p;              p += (size_t)N;
  int*      row_st   = (int*)(ws + p);      p += (size_t)N + 64;
  int*      cursor   = (int*)(ws + p);      p += (size_t)N;
  int*      srcp     = (int*)(ws + p);      p += (size_t)E2;
  float*    eap      = ws + p;              p += (size_t)E2;
  float*    logits   = ws + p;              p += (size_t)NA + 64;
  p = (p + 3) & ~(size_t)3;
  ushort* ub = (ushort*)(ws + p);
  size_t q = 0;
  ushort* xb   = ub + q; q += (size_t)N * F;
  ushort* wl1b = ub + q; q += (size_t)256 * 128;
  ushort* wr1b = ub + q; q += (size_t)256 * 128;
  ushort* wl2b = ub + q; q += (size_t)64 * 256;
  ushort* wr2b = ub + q; q += (size_t)64 * 256;
  ushort* xl1b = ub + q; q += (size_t)N * 256;
  ushort* xr1b = ub + q; q += (size_t)N * 256;
  ushort* h1b  = ub + q; q += (size_t)N * 256;
  ushort* xl2b = ub + q; q += (size_t)N * 64;
  ushort* xr2b = ub + q; q += (size_t)N * 64;

  float* out = (float*)d_out;

  hipMemsetAsync(d_ws, 0, zero_bytes, stream);

  // prep: casts + degree count + aflag, one launch
  {
    int n0 = N * F, n1 = 256 * 128, n2 = 256 * 128, n3 = 64 * 256, n4 = 64 * 256;
    int tot4 = (n0 + n1 + n2 + n3 + n4) / 4;
    int castB = (tot4 + 255) / 256;
    int cntB = (E + 255) / 256;
    k_prep<<<castB + cntB, 256, 0, stream>>>(
        x, xb, n0, Wl1, wl1b, n1, Wr1, wr1b, n2, Wl2, wl2b, n3, Wr2, wr2b, n4,
        dst, eattr, cnt_i, sum_ea, E, actions, aflag, n_act, castB);
  }

  k_scan<<<1, 1024, 0, stream>>>(cnt_i, sum_ea, mean_ea, row_st, cursor, N);

  // layer-1 GEMMs + CSR scatter in one launch
  {
    dim3 g1((N + 63) / 64, 4, 3);
    k_gemm_scatter<<<g1, 256, 0, stream>>>(xb, wl1b, bl1, xl1b, wr1b, br1, xr1b,
                                           N, 256, 128,
                                           dst, src, eattr, mean_ea, cursor,
                                           srcp, eap, E, E2);
  }
  k_fused1<<<(N + 7) / 8, 256, 0, stream>>>(xl1b, xr1b, srcp, eap, row_st,
                                            We1, att1, bias1, h1b, N);
  {
    dim3 g2((N + 63) / 64, 1, 2);
    k_gemm_mfma2<<<g2, 256, 0, stream>>>(h1b, wl2b, bl2, xl2b, wr2b, br2, xr2b,
                                         N, 64, 256);
  }
  k_fused2<<<(N + 31) / 32, 256, 0, stream>>>(xl2b, xr2b, srcp, eap, row_st,
                                              We2, att2, bias2, g_sum, N);

  k_logits<<<(NA + 63) / 64, 256, 0, stream>>>(
      g_sum, Wp, bp, alpha, Wf, bf, aflag, src, dst,
      logits, gmax_key, out, E, NA, 1.0f / (float)N);
  int nb4 = (NA + 1023) / 1024;
  k_exp<<<nb4, 256, 0, stream>>>(logits, gmax_key, gsum, NA);
  k_norm<<<nb4, 256, 0, stream>>>(logits, gsum, out, NA);
}